// Round 10
// baseline (435.611 us; speedup 1.0000x reference)
//
#include <hip/hip_runtime.h>
#include <hip/hip_bf16.h>

#define NATOMS 16384
#define MOLS   64
#define ATOMSM 256
#define EGB    524288
#define EGNN   262144
#define HID    128
#define NH     (NATOMS*HID)

#define OFFSETC 0.009f
#define ALPHAC  1.0f
#define BETAC   0.8f
#define GAMMAC  4.85f
#define PREFC   (-138.935456f*(1.0f-1.0f/78.5f))

typedef __hip_bfloat16 bf;
typedef __attribute__((ext_vector_type(8))) short bf8v;
typedef __attribute__((ext_vector_type(4))) float f4v;

__device__ __forceinline__ float b2f(bf x){ return __bfloat162float(x); }
__device__ __forceinline__ bf f2b(float x){ return __float2bfloat16(x); }
__device__ __forceinline__ short f2s(float x){ bf h = f2b(x); return *(short*)&h; }
__device__ __forceinline__ float sigf(float x){ return 1.0f/(1.0f+__expf(-x)); }
__device__ __forceinline__ float waveRed(float v){
    v += __shfl_xor(v,32); v += __shfl_xor(v,16); v += __shfl_xor(v,8);
    v += __shfl_xor(v,4);  v += __shfl_xor(v,2);  v += __shfl_xor(v,1);
    return v;
}

// ============ GB: LDS molecule-tile staged (round-9 proven) ============
__global__ __launch_bounds__(256) void k_gbA(
    const float* __restrict__ pos, const float* __restrict__ feat,
    const int* __restrict__ ei, float* __restrict__ Isum)
{
    __shared__ float sI[256];
    int tid = threadIdx.x;
    sI[tid] = 0.f;
    __syncthreads();
    int T = blockIdx.x*256 + tid;
    int s = T >> 3, p = T & 7;
    int e0 = s*32 + p*4;
    int mbase = (blockIdx.x >> 3) * 256;
    float px = pos[3*s+0], py = pos[3*s+1], pz = pos[3*s+2];
    float sr = feat[7*s+2] * (feat[7*s+1] - OFFSETC);
    const int* dP = ei + EGB;
#pragma unroll
    for (int j=0;j<4;j++){
        int dd = dP[e0+j];
        float dx = px - pos[3*dd+0];
        float dy = py - pos[3*dd+1];
        float dz = pz - pos[3*dd+2];
        float d  = sqrtf(dx*dx+dy*dy+dz*dz + 1e-12f);
        float rho_i = feat[7*dd+1] - OFFSETC;
        float U = d + sr;
        if (rho_i < U){
            float L = fmaxf(rho_i, fabsf(d - sr));
            float invU = 1.0f/U, invL = 1.0f/L;
            float I = 0.5f*invL - 0.5f*invU
                    + 0.125f*(d - sr*sr/d)*(invU*invU - invL*invL)
                    + 0.25f*__logf(L*invU)/d;
            atomicAdd(&sI[dd & 255], I);
        }
    }
    __syncthreads();
    atomicAdd(&Isum[mbase + tid], sI[tid]);
}

__global__ __launch_bounds__(256) void k_gbB(
    const float* __restrict__ feat, const float* __restrict__ Isum,
    float* __restrict__ Bv, float* __restrict__ cB, float* __restrict__ gB,
    float* __restrict__ egb)
{
    int i = blockIdx.x*256 + threadIdx.x;
    if (i >= NATOMS) return;
    float q   = feat[7*i+0];
    float rad = feat[7*i+1];
    float rho = rad - OFFSETC;
    float psi = Isum[i]*rho;
    float u = psi*(ALPHAC + psi*(-BETAC + GAMMAC*psi));
    float t = tanhf(u);
    float B = 1.0f/(1.0f/rho - t/rad);
    Bv[i] = B;
    float du = ALPHAC + psi*(-2.0f*BETAC + 3.0f*GAMMAC*psi);
    cB[i] = B*B*((1.0f-t*t)/rad)*du*rho;
    float Cs = 0.5f*PREFC*q*q;
    egb[i] = Cs/B;
    gB[i]  = -Cs/(B*B);
}

__global__ __launch_bounds__(256) void k_gbC(
    const float* __restrict__ pos, const float* __restrict__ feat,
    const int* __restrict__ ei, const float* __restrict__ Bv,
    float* __restrict__ egb, float* __restrict__ gdgb, float* __restrict__ gB)
{
    __shared__ float sE[256], sG[256];
    int tid = threadIdx.x;
    sE[tid]=0.f; sG[tid]=0.f;
    __syncthreads();
    int T = blockIdx.x*256 + tid;
    int s = T >> 3, p = T & 7;
    int e0 = s*32 + p*4;
    int mbase = (blockIdx.x >> 3) * 256;
    float px = pos[3*s+0], py = pos[3*s+1], pz = pos[3*s+2];
    float qs = feat[7*s+0];
    float Bs = Bv[s];
    float gsrc = 0.f;
    const int* dP = ei + EGB;
#pragma unroll
    for (int j=0;j<4;j++){
        int dd = dP[e0+j];
        float dx = px - pos[3*dd+0];
        float dy = py - pos[3*dd+1];
        float dz = pz - pos[3*dd+2];
        float d2 = dx*dx+dy*dy+dz*dz + 1e-12f;
        float d  = sqrtf(d2);
        float Bd = Bv[dd];
        float C = 0.5f*PREFC*feat[7*dd+0]*qs;
        float P = Bd*Bs;
        float ex = __expf(-d2/(4.f*P));
        float f2 = d2 + P*ex;
        float f  = sqrtf(f2);
        float f3i = 1.f/(f2*f);
        gdgb[e0+j] = -C*d*(1.f - 0.25f*ex)*f3i;
        float common = -C*ex*(1.f + d2/(4.f*P))*0.5f*f3i;
        atomicAdd(&sE[dd & 255], C/f);
        atomicAdd(&sG[dd & 255], common*Bs);
        gsrc += common*Bd;
    }
    gsrc += __shfl_xor(gsrc,1);
    gsrc += __shfl_xor(gsrc,2);
    gsrc += __shfl_xor(gsrc,4);
    if (p==0) atomicAdd(&sG[s & 255], gsrc);
    __syncthreads();
    atomicAdd(&egb[mbase + tid], sE[tid]);
    atomicAdd(&gB[mbase + tid],  sG[tid]);
}

__global__ __launch_bounds__(256) void k_gbD(
    const float* __restrict__ gB, float* __restrict__ cB)
{
    int i = blockIdx.x*256 + threadIdx.x;
    if (i < NATOMS) cB[i] *= gB[i];
}

__global__ __launch_bounds__(256) void k_gbE(
    const float* __restrict__ pos, const float* __restrict__ feat,
    const int* __restrict__ ei, const float* __restrict__ cBg,
    const float* __restrict__ gdgb, float* __restrict__ grad)
{
    __shared__ float sGx[256], sGy[256], sGz[256];
    int tid = threadIdx.x;
    sGx[tid]=0.f; sGy[tid]=0.f; sGz[tid]=0.f;
    __syncthreads();
    int T = blockIdx.x*256 + tid;
    int s = T >> 3, p = T & 7;
    int e0 = s*32 + p*4;
    int mbase = (blockIdx.x >> 3) * 256;
    float px = pos[3*s+0], py = pos[3*s+1], pz = pos[3*s+2];
    float sr = feat[7*s+2] * (feat[7*s+1] - OFFSETC);
    float gx=0.f, gy=0.f, gz=0.f;
    const int* dP = ei + EGB;
#pragma unroll
    for (int j=0;j<4;j++){
        int dd = dP[e0+j];
        float dx = px - pos[3*dd+0];
        float dy = py - pos[3*dd+1];
        float dz = pz - pos[3*dd+2];
        float d2 = dx*dx+dy*dy+dz*dz + 1e-12f;
        float d  = sqrtf(d2);
        float rho_i = feat[7*dd+1] - OFFSETC;
        float U = d + sr;
        float gd = gdgb[e0+j];
        if (rho_i < U){
            float aa = fabsf(d - sr);
            float L, Lp;
            if (rho_i >= aa){ L = rho_i; Lp = 0.f; }
            else { L = aa; Lp = (d >= sr) ? 1.f : -1.f; }
            float invU = 1.f/U, invL = 1.f/L;
            float invU2=invU*invU, invL2=invL*invL;
            float dIdd = -0.5f*Lp*invL2 + 0.5f*invU2
                + 0.125f*(1.f + sr*sr/d2)*(invU2 - invL2)
                + 0.125f*(d - sr*sr/d)*(2.f*Lp*invL2*invL - 2.f*invU2*invU)
                + 0.25f*((Lp*invL - invU)/d - __logf(L*invU)/d2);
            gd += cBg[dd]*dIdd;
        }
        float c = gd/d;
        gx += c*dx; gy += c*dy; gz += c*dz;
        int dl = dd & 255;
        atomicAdd(&sGx[dl], -c*dx);
        atomicAdd(&sGy[dl], -c*dy);
        atomicAdd(&sGz[dl], -c*dz);
    }
    gx += __shfl_xor(gx,1); gx += __shfl_xor(gx,2); gx += __shfl_xor(gx,4);
    gy += __shfl_xor(gy,1); gy += __shfl_xor(gy,2); gy += __shfl_xor(gy,4);
    gz += __shfl_xor(gz,1); gz += __shfl_xor(gz,2); gz += __shfl_xor(gz,4);
    if (p==0){
        int sl = s & 255;
        atomicAdd(&sGx[sl], gx);
        atomicAdd(&sGy[sl], gy);
        atomicAdd(&sGz[sl], gz);
    }
    __syncthreads();
    int i = mbase + tid;
    atomicAdd(&grad[3*i+0], sGx[tid]);
    atomicAdd(&grad[3*i+1], sGy[tid]);
    atomicAdd(&grad[3*i+2], sGz[tid]);
}

// ---------------- GNN: dist + CSR build ----------------
__global__ __launch_bounds__(256) void k_dist(
    const float* __restrict__ pos, const int* __restrict__ gei,
    float* __restrict__ dgnn, int* __restrict__ cnt)
{
    int e = blockIdx.x*256 + threadIdx.x;
    if (e >= EGNN) return;
    int s = gei[e], dd = gei[EGNN+e];
    float dx = pos[3*s+0] - pos[3*dd+0];
    float dy = pos[3*s+1] - pos[3*dd+1];
    float dz = pos[3*s+2] - pos[3*dd+2];
    dgnn[e] = sqrtf(dx*dx+dy*dy+dz*dz + 1e-12f);
    atomicAdd(&cnt[dd], 1);
}

__global__ __launch_bounds__(256) void k_scan(
    const int* __restrict__ cnt, int* __restrict__ rptr, int* __restrict__ cursor)
{
    __shared__ int sc[256];
    int m = blockIdx.x, t = threadIdx.x;
    int c = cnt[m*256+t];
    sc[t] = c; __syncthreads();
    for (int off=1; off<256; off<<=1){
        int x = (t>=off) ? sc[t-off] : 0;
        __syncthreads();
        sc[t] += x;
        __syncthreads();
    }
    int ex = m*4096 + sc[t] - c;
    rptr[m*256+t] = ex;
    cursor[m*256+t] = ex;
}

__global__ __launch_bounds__(256) void k_fill(
    const int* __restrict__ gei, int* __restrict__ cursor, int* __restrict__ csr)
{
    int e = blockIdx.x*256 + threadIdx.x;
    if (e >= EGNN) return;
    int dst = gei[EGNN+e];
    int pos = atomicAdd(&cursor[dst], 1);
    csr[pos] = e;
}

// ---------------- weight prep ----------------
__global__ __launch_bounds__(256) void k_wprep(
    const float* __restrict__ A2, const float* __restrict__ C1,
    const float* __restrict__ A3, const float* __restrict__ C2,
    short* __restrict__ C1t, short* __restrict__ C2t,
    short* __restrict__ A2at, short* __restrict__ A2bt,
    short* __restrict__ A3at, short* __restrict__ A3bt,
    short* __restrict__ rA2a, short* __restrict__ rA2b,
    short* __restrict__ rA3a, short* __restrict__ rA3b,
    short* __restrict__ rC1, short* __restrict__ rC2)
{
    int gid = blockIdx.x*256 + threadIdx.x;
    int j = gid >> 7, k = gid & 127;
    C1t[gid]  = f2s(C1[k*HID+j]);
    C2t[gid]  = f2s(C2[k*HID+j]);
    A2at[gid] = f2s(A2[k*HID+j]);
    A2bt[gid] = f2s(A2[(HID+k)*HID+j]);
    A3at[gid] = f2s(A3[k*HID+j]);
    A3bt[gid] = f2s(A3[(HID+k)*HID+j]);
    rA2a[gid] = f2s(A2[gid]);
    rA2b[gid] = f2s(A2[HID*HID+gid]);
    rA3a[gid] = f2s(A3[gid]);
    rA3b[gid] = f2s(A3[HID*HID+gid]);
    rC1[gid]  = f2s(C1[gid]);
    rC2[gid]  = f2s(C2[gid]);
}

// ---------------- GNN compute ----------------
__global__ __launch_bounds__(256) void k_uv1(
    const float* __restrict__ feat, const float* __restrict__ A1,
    bf* __restrict__ u1, bf* __restrict__ v1)
{
    int gid = blockIdx.x*256 + threadIdx.x;
    int i = gid >> 7, k = gid & 127;
    float q = feat[7*i+0], r = feat[7*i+1];
    u1[gid] = f2b(q*A1[k]       + r*A1[HID+k]);
    v1[gid] = f2b(q*A1[2*HID+k] + r*A1[3*HID+k]);
}

// dst-centric forward + silu' cache: Hs (bf16) + ds[e][k] (bf16)
__global__ __launch_bounds__(128) void k_edge_fwd_dst(
    const int* __restrict__ csr, const int* __restrict__ rptr, const int* __restrict__ cnt,
    const float* __restrict__ dgnn, const bf* __restrict__ u, const bf* __restrict__ v,
    const float* __restrict__ wdp, const float* __restrict__ bb,
    bf* __restrict__ Hs, bf* __restrict__ dsO)
{
    __shared__ int ss[128]; __shared__ int se_[128]; __shared__ float sd[128];
    int dst = blockIdx.x, k = threadIdx.x;
    int n = cnt[dst], r0 = rptr[dst];
    if (k < n){ int e = csr[r0+k]; ss[k] = e>>4; se_[k] = e; sd[k] = dgnn[e]; }
    __syncthreads();
    float vk = b2f(v[dst*HID+k]), wd = wdp[k], bk = bb[k];
    float hsum = 0.f;
    for (int j=0;j<n;j++){
        float a = b2f(u[ss[j]*HID+k]) + vk + sd[j]*wd + bk;
        float sg = sigf(a);
        hsum += a*sg;
        dsO[(size_t)se_[j]*HID + k] = f2b(sg*(1.f + a*(1.f - sg)));
    }
    Hs[dst*HID+k] = f2b(hsum);
}

// MFMA node forward (Hs bf16 in): z = Hs@C + cnt*D ; x=silu(z) ; u=x@Aa ; v=x@Ab
__global__ __launch_bounds__(256) void k_node_fwd_uv_mfma(
    const short* __restrict__ Hs, const int* __restrict__ cnt,
    const short* __restrict__ Ct, const float* __restrict__ D,
    const short* __restrict__ Aat, const short* __restrict__ Abt,
    float* __restrict__ z, bf* __restrict__ u, bf* __restrict__ v)
{
    __shared__ short sx[64*HID];
    int lane = threadIdx.x & 63, w = threadIdx.x >> 6;
    int m0 = blockIdx.x*64 + w*16;
    int ar = lane & 15, kg = lane >> 4;
    bf8v af[4];
#pragma unroll
    for (int s=0;s<4;s++) af[s] = *(const bf8v*)&Hs[(size_t)(m0+ar)*HID + s*32 + kg*8];
    f4v acc[8];
#pragma unroll
    for (int nt=0;nt<8;nt++){
        acc[nt] = (f4v){0.f,0.f,0.f,0.f};
        const short* bp = Ct + (nt*16+ar)*HID + kg*8;
#pragma unroll
        for (int s=0;s<4;s++){
            bf8v bv = *(const bf8v*)(bp + s*32);
            acc[nt] = __builtin_amdgcn_mfma_f32_16x16x32_bf16(af[s], bv, acc[nt], 0,0,0);
        }
    }
    float cn[4];
#pragma unroll
    for (int r=0;r<4;r++) cn[r] = (float)cnt[m0 + kg*4 + r];
#pragma unroll
    for (int nt=0;nt<8;nt++){
        int j = nt*16 + ar;
        float Dj = D[j];
#pragma unroll
        for (int r=0;r<4;r++){
            int m = m0 + kg*4 + r;
            float zv = acc[nt][r] + cn[r]*Dj;
            z[(size_t)m*HID + j] = zv;
            float xv = zv*sigf(zv);
            sx[(w*16 + kg*4 + r)*HID + j] = f2s(xv);
        }
    }
    __syncthreads();
#pragma unroll
    for (int s=0;s<4;s++) af[s] = *(const bf8v*)&sx[(w*16+ar)*HID + s*32 + kg*8];
    f4v au[8], av[8];
#pragma unroll
    for (int nt=0;nt<8;nt++){
        au[nt] = (f4v){0.f,0.f,0.f,0.f};
        av[nt] = (f4v){0.f,0.f,0.f,0.f};
        const short* bpa = Aat + (nt*16+ar)*HID + kg*8;
        const short* bpb = Abt + (nt*16+ar)*HID + kg*8;
#pragma unroll
        for (int s=0;s<4;s++){
            bf8v ba = *(const bf8v*)(bpa + s*32);
            bf8v bb = *(const bf8v*)(bpb + s*32);
            au[nt] = __builtin_amdgcn_mfma_f32_16x16x32_bf16(af[s], ba, au[nt], 0,0,0);
            av[nt] = __builtin_amdgcn_mfma_f32_16x16x32_bf16(af[s], bb, av[nt], 0,0,0);
        }
    }
#pragma unroll
    for (int nt=0;nt<8;nt++){
        int j = nt*16 + ar;
#pragma unroll
        for (int r=0;r<4;r++){
            int m = m0 + kg*4 + r;
            u[(size_t)m*HID + j] = f2b(au[nt][r]);
            v[(size_t)m*HID + j] = f2b(av[nt][r]);
        }
    }
}

// MFMA node backward (Gs/Gd bf16 in)
__global__ __launch_bounds__(256) void k_gx_node_bwd_mfma(
    const short* __restrict__ Gs, const short* __restrict__ Gd,
    const short* __restrict__ Ra, const short* __restrict__ Rb,
    const float* __restrict__ z, const short* __restrict__ Rc,
    bf* __restrict__ gH)
{
    __shared__ short st[64*HID];
    int lane = threadIdx.x & 63, w = threadIdx.x >> 6;
    int m0 = blockIdx.x*64 + w*16;
    int ar = lane & 15, kg = lane >> 4;
    bf8v as_[4], ad_[4];
#pragma unroll
    for (int s=0;s<4;s++){
        as_[s] = *(const bf8v*)&Gs[(size_t)(m0+ar)*HID + s*32 + kg*8];
        ad_[s] = *(const bf8v*)&Gd[(size_t)(m0+ar)*HID + s*32 + kg*8];
    }
    f4v acc[8];
#pragma unroll
    for (int nt=0;nt<8;nt++){
        acc[nt] = (f4v){0.f,0.f,0.f,0.f};
        const short* bpa = Ra + (nt*16+ar)*HID + kg*8;
        const short* bpb = Rb + (nt*16+ar)*HID + kg*8;
#pragma unroll
        for (int s=0;s<4;s++){
            bf8v ba = *(const bf8v*)(bpa + s*32);
            bf8v bb = *(const bf8v*)(bpb + s*32);
            acc[nt] = __builtin_amdgcn_mfma_f32_16x16x32_bf16(as_[s], ba, acc[nt], 0,0,0);
            acc[nt] = __builtin_amdgcn_mfma_f32_16x16x32_bf16(ad_[s], bb, acc[nt], 0,0,0);
        }
    }
#pragma unroll
    for (int nt=0;nt<8;nt++){
        int j = nt*16 + ar;
#pragma unroll
        for (int r=0;r<4;r++){
            int m = m0 + kg*4 + r;
            float zz = z[(size_t)m*HID + j];
            float sg = sigf(zz);
            float t = acc[nt][r]*sg*(1.f + zz*(1.f - sg));
            st[(w*16 + kg*4 + r)*HID + j] = f2s(t);
        }
    }
    __syncthreads();
    bf8v af[4];
#pragma unroll
    for (int s=0;s<4;s++) af[s] = *(const bf8v*)&st[(w*16+ar)*HID + s*32 + kg*8];
    f4v a2[8];
#pragma unroll
    for (int nt=0;nt<8;nt++){
        a2[nt] = (f4v){0.f,0.f,0.f,0.f};
        const short* bp = Rc + (nt*16+ar)*HID + kg*8;
#pragma unroll
        for (int s=0;s<4;s++){
            bf8v bc = *(const bf8v*)(bp + s*32);
            a2[nt] = __builtin_amdgcn_mfma_f32_16x16x32_bf16(af[s], bc, a2[nt], 0,0,0);
        }
    }
#pragma unroll
    for (int nt=0;nt<8;nt++){
        int j = nt*16 + ar;
#pragma unroll
        for (int r=0;r<4;r++){
            gH[(size_t)(m0 + kg*4 + r)*HID + j] = f2b(a2[nt][r]);
        }
    }
}

// l3 dst pass: computes a once; writes ds3[e], Gd3 (bf16), x3
__global__ __launch_bounds__(128) void k_l3_dst(
    const int* __restrict__ csr, const int* __restrict__ rptr, const int* __restrict__ cnt,
    const float* __restrict__ dgnn, const bf* __restrict__ u, const bf* __restrict__ v,
    const float* __restrict__ A3, const float* __restrict__ B3,
    const float* __restrict__ C3, const float* __restrict__ D3,
    bf* __restrict__ ds3, bf* __restrict__ Gd, float* __restrict__ x3)
{
    __shared__ int ss[128]; __shared__ int se_[128]; __shared__ float sd[128];
    __shared__ float rr[2];
    int dst = blockIdx.x, k = threadIdx.x;
    int n = cnt[dst], r0 = rptr[dst];
    if (k < n){ int e = csr[r0+k]; ss[k] = e>>4; se_[k] = e; sd[k] = dgnn[e]; }
    __syncthreads();
    float vk = b2f(v[dst*HID+k]), wd = A3[256*HID+k], bk = B3[k], ck = C3[k];
    float hsum = 0.f, dssum = 0.f;
    for (int j=0;j<n;j++){
        float a = b2f(u[ss[j]*HID+k]) + vk + sd[j]*wd + bk;
        float sg = sigf(a);
        hsum += a*sg;
        float dv = sg*(1.f + a*(1.f - sg));
        dssum += dv;
        ds3[(size_t)se_[j]*HID + k] = f2b(dv);
    }
    Gd[dst*HID+k] = f2b(ck*dssum);
    float pv = waveRed(ck*hsum);
    if ((k&63)==0) rr[k>>6] = pv;
    __syncthreads();
    if (k==0) x3[dst] = rr[0] + rr[1] + (float)n*D3[0];
}

// l3 src pass: pure ds3 stream -> Gs3 (bf16) + gdg (=)
__global__ __launch_bounds__(128) void k_l3_src(
    const bf* __restrict__ ds3,
    const float* __restrict__ A3, const float* __restrict__ C3,
    bf* __restrict__ Gs, float* __restrict__ gdg)
{
    __shared__ float sQ[16][130];
    int s = blockIdx.x, k = threadIdx.x;
    float wd = A3[256*HID+k], ck = C3[k];
    float cw = ck*wd;
    int e0 = s*16;
    float gs = 0.f;
#pragma unroll 4
    for (int t=0;t<16;t++){
        float dv = b2f(ds3[(size_t)(e0+t)*HID + k]);
        gs += dv;
        sQ[t][k] = dv*cw;
    }
    Gs[s*HID+k] = f2b(ck*gs);
    __syncthreads();
    int t = k >> 3, r = k & 7;
    float pg = 0.f;
#pragma unroll
    for (int i=0;i<16;i++) pg += sQ[t][i + 16*r];
    pg += __shfl_xor(pg,1); pg += __shfl_xor(pg,2); pg += __shfl_xor(pg,4);
    if (r==0) gdg[e0+t] = pg;
}

// merged layer-2 bwd src+dst (grid 2N), using cached ds2
__global__ __launch_bounds__(128) void k_bwd(
    const int* __restrict__ gei,
    const int* __restrict__ csr, const int* __restrict__ rptr, const int* __restrict__ cnt,
    const bf* __restrict__ ds2, const float* __restrict__ wdp,
    const bf* __restrict__ gH,
    bf* __restrict__ Gs, bf* __restrict__ Gd, float* __restrict__ gdg)
{
    int k = threadIdx.x;
    if (blockIdx.x < NATOMS){
        __shared__ float sQ[16][130];
        int s = blockIdx.x;
        float wd = wdp[k];
        int e0 = s*16;
        int dsts[16];
#pragma unroll
        for (int t=0;t<16;t++) dsts[t]=gei[EGNN+e0+t];
        float gs = 0.f;
#pragma unroll 4
        for (int t=0;t<16;t++){
            float ga = b2f(gH[dsts[t]*HID+k]) * b2f(ds2[(size_t)(e0+t)*HID+k]);
            gs += ga;
            sQ[t][k] = ga*wd;
        }
        Gs[s*HID+k] = f2b(gs);
        __syncthreads();
        int t = k >> 3, r = k & 7;
        float pg = 0.f;
#pragma unroll
        for (int i=0;i<16;i++) pg += sQ[t][i + 16*r];
        pg += __shfl_xor(pg,1); pg += __shfl_xor(pg,2); pg += __shfl_xor(pg,4);
        if (r==0) gdg[e0+t] += pg;
    } else {
        __shared__ int se_[128];
        int dst = blockIdx.x - NATOMS;
        int n = cnt[dst], r0 = rptr[dst];
        if (k < n) se_[k] = csr[r0+k];
        __syncthreads();
        float dssum = 0.f;
        for (int j=0;j<n;j++) dssum += b2f(ds2[(size_t)se_[j]*HID + k]);
        Gd[dst*HID+k] = f2b(b2f(gH[dst*HID+k])*dssum);
    }
}

// layer-1 bwd: stream ds1 + gather gH1 -> gdg +=
__global__ __launch_bounds__(128) void k_bwd1_src(
    const int* __restrict__ gei, const bf* __restrict__ ds1,
    const float* __restrict__ wdp, const bf* __restrict__ gH,
    float* __restrict__ gdg)
{
    __shared__ float sQ[16][130];
    int s = blockIdx.x, k = threadIdx.x;
    float wd = wdp[k];
    int e0 = s*16;
    int dsts[16];
#pragma unroll
    for (int t=0;t<16;t++) dsts[t]=gei[EGNN+e0+t];
#pragma unroll 4
    for (int t=0;t<16;t++){
        float ga = b2f(gH[dsts[t]*HID+k]) * b2f(ds1[(size_t)(e0+t)*HID+k]);
        sQ[t][k] = ga*wd;
    }
    __syncthreads();
    int t = k >> 3, r = k & 7;
    float pg = 0.f;
#pragma unroll
    for (int i=0;i<16;i++) pg += sQ[t][i + 16*r];
    pg += __shfl_xor(pg,1); pg += __shfl_xor(pg,2); pg += __shfl_xor(pg,4);
    if (r==0) gdg[e0+t] += pg;
}

__global__ __launch_bounds__(256) void k_force_atom(
    const float* __restrict__ pos, const int* __restrict__ gei,
    const int* __restrict__ csr, const int* __restrict__ rptr, const int* __restrict__ cnt,
    const float* __restrict__ dgnn, const float* __restrict__ gdg,
    float* __restrict__ grad)
{
    int T = blockIdx.x*256 + threadIdx.x;
    int i = T >> 3, p = T & 7;
    float px = pos[3*i+0], py = pos[3*i+1], pz = pos[3*i+2];
    float ax=0.f, ay=0.f, az=0.f;
    for (int j=p;j<16;j+=8){
        int e = i*16 + j;
        int o = gei[EGNN+e];
        float c = gdg[e]/dgnn[e];
        ax += c*(px - pos[3*o+0]);
        ay += c*(py - pos[3*o+1]);
        az += c*(pz - pos[3*o+2]);
    }
    int n = cnt[i], r0 = rptr[i];
    for (int j=p;j<n;j+=8){
        int e = csr[r0+j];
        int o = e >> 4;
        float c = gdg[e]/dgnn[e];
        ax += c*(px - pos[3*o+0]);
        ay += c*(py - pos[3*o+1]);
        az += c*(pz - pos[3*o+2]);
    }
    ax += __shfl_xor(ax,1); ax += __shfl_xor(ax,2); ax += __shfl_xor(ax,4);
    ay += __shfl_xor(ay,1); ay += __shfl_xor(ay,2); ay += __shfl_xor(ay,4);
    az += __shfl_xor(az,1); az += __shfl_xor(az,2); az += __shfl_xor(az,4);
    if (p==0){
        grad[3*i+0] += ax;
        grad[3*i+1] += ay;
        grad[3*i+2] += az;
    }
}

__global__ __launch_bounds__(256) void k_final(
    const float* __restrict__ egb, const float* __restrict__ x3,
    const float* __restrict__ grad, float* __restrict__ out)
{
    __shared__ float red[4];
    int m = blockIdx.x, tid = threadIdx.x;
    int i = m*ATOMSM + tid;
    float en = egb[i] + x3[i];
    float v = waveRed(en);
    int wave = tid>>6, lane = tid&63;
    if (lane==0) red[wave] = v;
    __syncthreads();
    if (tid==0) out[m] = red[0]+red[1]+red[2]+red[3];
    float* f = out + MOLS;
    f[3*i+0] = -grad[3*i+0];
    f[3*i+1] = -grad[3*i+1];
    f[3*i+2] = -grad[3*i+2];
}

extern "C" void kernel_launch(void* const* d_in, const int* in_sizes, int n_in,
                              void* d_out, int out_size, void* d_ws, size_t ws_size,
                              hipStream_t stream)
{
    const float* pos  = (const float*)d_in[0];
    const float* feat = (const float*)d_in[1];
    const int* ei  = (const int*)d_in[3];
    const int* gei = (const int*)d_in[4];
    const float* A1f = (const float*)d_in[5];  const float* B1f = (const float*)d_in[6];
    const float* C1f = (const float*)d_in[7];  const float* D1f = (const float*)d_in[8];
    const float* A2f = (const float*)d_in[9];  const float* B2f = (const float*)d_in[10];
    const float* C2f = (const float*)d_in[11]; const float* D2f = (const float*)d_in[12];
    const float* A3f = (const float*)d_in[13]; const float* B3f = (const float*)d_in[14];
    const float* C3f = (const float*)d_in[15]; const float* D3f = (const float*)d_in[16];

    float* w = (float*)d_ws;
    size_t off = 0;
    auto nxt = [&](size_t n)->float*{ float* p = w + off; off += (n + 255) & ~(size_t)255; return p; };
    float* Isum = nxt(NATOMS); float* Bv = nxt(NATOMS); float* cB = nxt(NATOMS);
    float* gB = nxt(NATOMS); float* egb = nxt(NATOMS); float* x3 = nxt(NATOMS);
    int*   cnt  = (int*)nxt(NATOMS);
    int*   rptr = (int*)nxt(NATOMS);
    int*   curs = (int*)nxt(NATOMS);
    int*   csr  = (int*)nxt(EGNN);
    float* dgnn = nxt(EGNN); float* gdgnn = nxt(EGNN); float* gdgb = nxt(EGB);
    float* grad = nxt(3*NATOMS);
    float* z1 = nxt(NH); float* z2 = nxt(NH);
    bf* Hs1 = (bf*)nxt(NH/2); bf* Hs2 = (bf*)nxt(NH/2);
    bf* Gs3 = (bf*)nxt(NH/2); bf* Gd3 = (bf*)nxt(NH/2);
    bf* u1 = (bf*)nxt(NH/2); bf* v1 = (bf*)nxt(NH/2);
    bf* u2 = (bf*)nxt(NH/2); bf* v2 = (bf*)nxt(NH/2);
    bf* v3 = (bf*)nxt(NH/2);
    short* C1t  = (short*)nxt(8192); short* C2t  = (short*)nxt(8192);
    short* A2at = (short*)nxt(8192); short* A2bt = (short*)nxt(8192);
    short* A3at = (short*)nxt(8192); short* A3bt = (short*)nxt(8192);
    short* rA2a = (short*)nxt(8192); short* rA2b = (short*)nxt(8192);
    short* rA3a = (short*)nxt(8192); short* rA3b = (short*)nxt(8192);
    short* rC1  = (short*)nxt(8192); short* rC2  = (short*)nxt(8192);
    // silu' caches: EGNN*HID bf16 each (= EGNN*HID/2 floats)
    bf* ds1 = (bf*)nxt((size_t)EGNN*HID/2);
    bf* ds2 = (bf*)nxt((size_t)EGNN*HID/2);
    bf* ds3 = (bf*)nxt((size_t)EGNN*HID/2);
    // aliases:
    bf* u3  = Hs1;      // Hs1 dead after node_fwd #1
    bf* gH2 = Hs2;      // Hs2 dead after node_fwd #2
    bf* Gs2 = Gs3;      // dead after gx_node_bwd(3->2)
    bf* Gd2 = Gd3;
    bf* gH1 = u3;       // u3 dead after l3 passes

    hipMemsetAsync(Isum, 0, NATOMS*sizeof(float), stream);
    hipMemsetAsync(cnt,  0, NATOMS*sizeof(int), stream);
    hipMemsetAsync(grad, 0, 3*NATOMS*sizeof(float), stream);

    k_wprep<<<64,256,0,stream>>>(A2f, C1f, A3f, C2f,
        C1t, C2t, A2at, A2bt, A3at, A3bt, rA2a, rA2b, rA3a, rA3b, rC1, rC2);

    // GB chain
    k_gbA<<<512,256,0,stream>>>(pos, feat, ei, Isum);
    k_gbB<<<NATOMS/256,256,0,stream>>>(feat, Isum, Bv, cB, gB, egb);
    k_gbC<<<512,256,0,stream>>>(pos, feat, ei, Bv, egb, gdgb, gB);
    k_gbD<<<NATOMS/256,256,0,stream>>>(gB, cB);
    k_gbE<<<512,256,0,stream>>>(pos, feat, ei, cB, gdgb, grad);

    // dist + CSR build
    k_dist<<<EGNN/256,256,0,stream>>>(pos, gei, dgnn, cnt);
    k_scan<<<MOLS,256,0,stream>>>(cnt, rptr, curs);
    k_fill<<<EGNN/256,256,0,stream>>>(gei, curs, csr);

    // forward (with silu' caching)
    k_uv1<<<NH/256,256,0,stream>>>(feat, A1f, u1, v1);
    k_edge_fwd_dst<<<NATOMS,128,0,stream>>>(csr, rptr, cnt, dgnn, u1, v1,
                                            A1f+4*HID, B1f, Hs1, ds1);
    k_node_fwd_uv_mfma<<<NATOMS/64,256,0,stream>>>((const short*)Hs1, cnt, C1t, D1f,
                                                   A2at, A2bt, z1, u2, v2);
    k_edge_fwd_dst<<<NATOMS,128,0,stream>>>(csr, rptr, cnt, dgnn, u2, v2,
                                            A2f+256*HID, B2f, Hs2, ds2);
    k_node_fwd_uv_mfma<<<NATOMS/64,256,0,stream>>>((const short*)Hs2, cnt, C2t, D2f,
                                                   A3at, A3bt, z2, u3, v3);

    // layer-3: dst (compute+cache) then src (stream)
    k_l3_dst<<<NATOMS,128,0,stream>>>(csr, rptr, cnt, dgnn, u3, v3,
                                      A3f, B3f, C3f, D3f, ds3, Gd3, x3);
    k_l3_src<<<NATOMS,128,0,stream>>>(ds3, A3f, C3f, Gs3, gdgnn);

    // backward chain
    k_gx_node_bwd_mfma<<<NATOMS/64,256,0,stream>>>((const short*)Gs3, (const short*)Gd3,
                                                   rA3a, rA3b, z2, rC2, gH2);
    k_bwd<<<2*NATOMS,128,0,stream>>>(gei, csr, rptr, cnt, ds2, A2f+256*HID,
                                     gH2, Gs2, Gd2, gdgnn);
    k_gx_node_bwd_mfma<<<NATOMS/64,256,0,stream>>>((const short*)Gs2, (const short*)Gd2,
                                                   rA2a, rA2b, z1, rC1, gH1);
    k_bwd1_src<<<NATOMS,128,0,stream>>>(gei, ds1, A1f+4*HID, gH1, gdgnn);
    k_force_atom<<<NATOMS*8/256,256,0,stream>>>(pos, gei, csr, rptr, cnt, dgnn, gdgnn, grad);

    k_final<<<MOLS,256,0,stream>>>(egb, x3, grad, (float*)d_out);
}

// Round 11
// 402.546 us; speedup vs baseline: 1.0821x; 1.0821x over previous
//
#include <hip/hip_runtime.h>
#include <hip/hip_bf16.h>

#define NATOMS 16384
#define MOLS   64
#define ATOMSM 256
#define EGB    524288
#define EGNN   262144
#define HID    128
#define NH     (NATOMS*HID)

#define OFFSETC 0.009f
#define ALPHAC  1.0f
#define BETAC   0.8f
#define GAMMAC  4.85f
#define PREFC   (-138.935456f*(1.0f-1.0f/78.5f))

typedef __hip_bfloat16 bf;
typedef __attribute__((ext_vector_type(8))) short bf8v;
typedef __attribute__((ext_vector_type(4))) float f4v;

__device__ __forceinline__ float b2f(bf x){ return __bfloat162float(x); }
__device__ __forceinline__ bf f2b(float x){ return __float2bfloat16(x); }
__device__ __forceinline__ short f2s(float x){ bf h = f2b(x); return *(short*)&h; }
__device__ __forceinline__ float s2f(short s){
    unsigned int x = ((unsigned int)(unsigned short)s) << 16;
    return __uint_as_float(x);
}
__device__ __forceinline__ float sigf(float x){ return 1.0f/(1.0f+__expf(-x)); }
__device__ __forceinline__ float waveRed(float v){
    v += __shfl_xor(v,32); v += __shfl_xor(v,16); v += __shfl_xor(v,8);
    v += __shfl_xor(v,4);  v += __shfl_xor(v,2);  v += __shfl_xor(v,1);
    return v;
}

// ============ GB: LDS molecule-tile staged (round-9 proven) ============
__global__ __launch_bounds__(256) void k_gbA(
    const float* __restrict__ pos, const float* __restrict__ feat,
    const int* __restrict__ ei, float* __restrict__ Isum)
{
    __shared__ float sI[256];
    int tid = threadIdx.x;
    sI[tid] = 0.f;
    __syncthreads();
    int T = blockIdx.x*256 + tid;
    int s = T >> 3, p = T & 7;
    int e0 = s*32 + p*4;
    int mbase = (blockIdx.x >> 3) * 256;
    float px = pos[3*s+0], py = pos[3*s+1], pz = pos[3*s+2];
    float sr = feat[7*s+2] * (feat[7*s+1] - OFFSETC);
    const int* dP = ei + EGB;
#pragma unroll
    for (int j=0;j<4;j++){
        int dd = dP[e0+j];
        float dx = px - pos[3*dd+0];
        float dy = py - pos[3*dd+1];
        float dz = pz - pos[3*dd+2];
        float d  = sqrtf(dx*dx+dy*dy+dz*dz + 1e-12f);
        float rho_i = feat[7*dd+1] - OFFSETC;
        float U = d + sr;
        if (rho_i < U){
            float L = fmaxf(rho_i, fabsf(d - sr));
            float invU = 1.0f/U, invL = 1.0f/L;
            float I = 0.5f*invL - 0.5f*invU
                    + 0.125f*(d - sr*sr/d)*(invU*invU - invL*invL)
                    + 0.25f*__logf(L*invU)/d;
            atomicAdd(&sI[dd & 255], I);
        }
    }
    __syncthreads();
    atomicAdd(&Isum[mbase + tid], sI[tid]);
}

__global__ __launch_bounds__(256) void k_gbB(
    const float* __restrict__ feat, const float* __restrict__ Isum,
    float* __restrict__ Bv, float* __restrict__ cB, float* __restrict__ gB,
    float* __restrict__ egb)
{
    int i = blockIdx.x*256 + threadIdx.x;
    if (i >= NATOMS) return;
    float q   = feat[7*i+0];
    float rad = feat[7*i+1];
    float rho = rad - OFFSETC;
    float psi = Isum[i]*rho;
    float u = psi*(ALPHAC + psi*(-BETAC + GAMMAC*psi));
    float t = tanhf(u);
    float B = 1.0f/(1.0f/rho - t/rad);
    Bv[i] = B;
    float du = ALPHAC + psi*(-2.0f*BETAC + 3.0f*GAMMAC*psi);
    cB[i] = B*B*((1.0f-t*t)/rad)*du*rho;
    float Cs = 0.5f*PREFC*q*q;
    egb[i] = Cs/B;
    gB[i]  = -Cs/(B*B);
}

__global__ __launch_bounds__(256) void k_gbC(
    const float* __restrict__ pos, const float* __restrict__ feat,
    const int* __restrict__ ei, const float* __restrict__ Bv,
    float* __restrict__ egb, float* __restrict__ gdgb, float* __restrict__ gB)
{
    __shared__ float sE[256], sG[256];
    int tid = threadIdx.x;
    sE[tid]=0.f; sG[tid]=0.f;
    __syncthreads();
    int T = blockIdx.x*256 + tid;
    int s = T >> 3, p = T & 7;
    int e0 = s*32 + p*4;
    int mbase = (blockIdx.x >> 3) * 256;
    float px = pos[3*s+0], py = pos[3*s+1], pz = pos[3*s+2];
    float qs = feat[7*s+0];
    float Bs = Bv[s];
    float gsrc = 0.f;
    const int* dP = ei + EGB;
#pragma unroll
    for (int j=0;j<4;j++){
        int dd = dP[e0+j];
        float dx = px - pos[3*dd+0];
        float dy = py - pos[3*dd+1];
        float dz = pz - pos[3*dd+2];
        float d2 = dx*dx+dy*dy+dz*dz + 1e-12f;
        float d  = sqrtf(d2);
        float Bd = Bv[dd];
        float C = 0.5f*PREFC*feat[7*dd+0]*qs;
        float P = Bd*Bs;
        float ex = __expf(-d2/(4.f*P));
        float f2 = d2 + P*ex;
        float f  = sqrtf(f2);
        float f3i = 1.f/(f2*f);
        gdgb[e0+j] = -C*d*(1.f - 0.25f*ex)*f3i;
        float common = -C*ex*(1.f + d2/(4.f*P))*0.5f*f3i;
        atomicAdd(&sE[dd & 255], C/f);
        atomicAdd(&sG[dd & 255], common*Bs);
        gsrc += common*Bd;
    }
    gsrc += __shfl_xor(gsrc,1);
    gsrc += __shfl_xor(gsrc,2);
    gsrc += __shfl_xor(gsrc,4);
    if (p==0) atomicAdd(&sG[s & 255], gsrc);
    __syncthreads();
    atomicAdd(&egb[mbase + tid], sE[tid]);
    atomicAdd(&gB[mbase + tid],  sG[tid]);
}

__global__ __launch_bounds__(256) void k_gbD(
    const float* __restrict__ gB, float* __restrict__ cB)
{
    int i = blockIdx.x*256 + threadIdx.x;
    if (i < NATOMS) cB[i] *= gB[i];
}

__global__ __launch_bounds__(256) void k_gbE(
    const float* __restrict__ pos, const float* __restrict__ feat,
    const int* __restrict__ ei, const float* __restrict__ cBg,
    const float* __restrict__ gdgb, float* __restrict__ grad)
{
    __shared__ float sGx[256], sGy[256], sGz[256];
    int tid = threadIdx.x;
    sGx[tid]=0.f; sGy[tid]=0.f; sGz[tid]=0.f;
    __syncthreads();
    int T = blockIdx.x*256 + tid;
    int s = T >> 3, p = T & 7;
    int e0 = s*32 + p*4;
    int mbase = (blockIdx.x >> 3) * 256;
    float px = pos[3*s+0], py = pos[3*s+1], pz = pos[3*s+2];
    float sr = feat[7*s+2] * (feat[7*s+1] - OFFSETC);
    float gx=0.f, gy=0.f, gz=0.f;
    const int* dP = ei + EGB;
#pragma unroll
    for (int j=0;j<4;j++){
        int dd = dP[e0+j];
        float dx = px - pos[3*dd+0];
        float dy = py - pos[3*dd+1];
        float dz = pz - pos[3*dd+2];
        float d2 = dx*dx+dy*dy+dz*dz + 1e-12f;
        float d  = sqrtf(d2);
        float rho_i = feat[7*dd+1] - OFFSETC;
        float U = d + sr;
        float gd = gdgb[e0+j];
        if (rho_i < U){
            float aa = fabsf(d - sr);
            float L, Lp;
            if (rho_i >= aa){ L = rho_i; Lp = 0.f; }
            else { L = aa; Lp = (d >= sr) ? 1.f : -1.f; }
            float invU = 1.f/U, invL = 1.f/L;
            float invU2=invU*invU, invL2=invL*invL;
            float dIdd = -0.5f*Lp*invL2 + 0.5f*invU2
                + 0.125f*(1.f + sr*sr/d2)*(invU2 - invL2)
                + 0.125f*(d - sr*sr/d)*(2.f*Lp*invL2*invL - 2.f*invU2*invU)
                + 0.25f*((Lp*invL - invU)/d - __logf(L*invU)/d2);
            gd += cBg[dd]*dIdd;
        }
        float c = gd/d;
        gx += c*dx; gy += c*dy; gz += c*dz;
        int dl = dd & 255;
        atomicAdd(&sGx[dl], -c*dx);
        atomicAdd(&sGy[dl], -c*dy);
        atomicAdd(&sGz[dl], -c*dz);
    }
    gx += __shfl_xor(gx,1); gx += __shfl_xor(gx,2); gx += __shfl_xor(gx,4);
    gy += __shfl_xor(gy,1); gy += __shfl_xor(gy,2); gy += __shfl_xor(gy,4);
    gz += __shfl_xor(gz,1); gz += __shfl_xor(gz,2); gz += __shfl_xor(gz,4);
    if (p==0){
        int sl = s & 255;
        atomicAdd(&sGx[sl], gx);
        atomicAdd(&sGy[sl], gy);
        atomicAdd(&sGz[sl], gz);
    }
    __syncthreads();
    int i = mbase + tid;
    atomicAdd(&grad[3*i+0], sGx[tid]);
    atomicAdd(&grad[3*i+1], sGy[tid]);
    atomicAdd(&grad[3*i+2], sGz[tid]);
}

// ---------------- GNN: dist + CSR build ----------------
__global__ __launch_bounds__(256) void k_dist(
    const float* __restrict__ pos, const int* __restrict__ gei,
    float* __restrict__ dgnn, int* __restrict__ cnt)
{
    int e = blockIdx.x*256 + threadIdx.x;
    if (e >= EGNN) return;
    int s = gei[e], dd = gei[EGNN+e];
    float dx = pos[3*s+0] - pos[3*dd+0];
    float dy = pos[3*s+1] - pos[3*dd+1];
    float dz = pos[3*s+2] - pos[3*dd+2];
    dgnn[e] = sqrtf(dx*dx+dy*dy+dz*dz + 1e-12f);
    atomicAdd(&cnt[dd], 1);
}

__global__ __launch_bounds__(256) void k_scan(
    const int* __restrict__ cnt, int* __restrict__ rptr, int* __restrict__ cursor)
{
    __shared__ int sc[256];
    int m = blockIdx.x, t = threadIdx.x;
    int c = cnt[m*256+t];
    sc[t] = c; __syncthreads();
    for (int off=1; off<256; off<<=1){
        int x = (t>=off) ? sc[t-off] : 0;
        __syncthreads();
        sc[t] += x;
        __syncthreads();
    }
    int ex = m*4096 + sc[t] - c;
    rptr[m*256+t] = ex;
    cursor[m*256+t] = ex;
}

__global__ __launch_bounds__(256) void k_fill(
    const int* __restrict__ gei, int* __restrict__ cursor, int* __restrict__ csr)
{
    int e = blockIdx.x*256 + threadIdx.x;
    if (e >= EGNN) return;
    int dst = gei[EGNN+e];
    int pos = atomicAdd(&cursor[dst], 1);
    csr[pos] = e;
}

// ---------------- weight prep ----------------
__global__ __launch_bounds__(256) void k_wprep(
    const float* __restrict__ A2, const float* __restrict__ C1,
    const float* __restrict__ A3, const float* __restrict__ C2,
    short* __restrict__ C1t, short* __restrict__ C2t,
    short* __restrict__ A2at, short* __restrict__ A2bt,
    short* __restrict__ A3at, short* __restrict__ A3bt,
    short* __restrict__ rA2a, short* __restrict__ rA2b,
    short* __restrict__ rA3a, short* __restrict__ rA3b,
    short* __restrict__ rC1, short* __restrict__ rC2)
{
    int gid = blockIdx.x*256 + threadIdx.x;
    int j = gid >> 7, k = gid & 127;
    C1t[gid]  = f2s(C1[k*HID+j]);
    C2t[gid]  = f2s(C2[k*HID+j]);
    A2at[gid] = f2s(A2[k*HID+j]);
    A2bt[gid] = f2s(A2[(HID+k)*HID+j]);
    A3at[gid] = f2s(A3[k*HID+j]);
    A3bt[gid] = f2s(A3[(HID+k)*HID+j]);
    rA2a[gid] = f2s(A2[gid]);
    rA2b[gid] = f2s(A2[HID*HID+gid]);
    rA3a[gid] = f2s(A3[gid]);
    rA3b[gid] = f2s(A3[HID*HID+gid]);
    rC1[gid]  = f2s(C1[gid]);
    rC2[gid]  = f2s(C2[gid]);
}

// ---------------- GNN compute ----------------
__global__ __launch_bounds__(256) void k_uv1(
    const float* __restrict__ feat, const float* __restrict__ A1,
    bf* __restrict__ u1, bf* __restrict__ v1)
{
    int gid = blockIdx.x*256 + threadIdx.x;
    int i = gid >> 7, k = gid & 127;
    float q = feat[7*i+0], r = feat[7*i+1];
    u1[gid] = f2b(q*A1[k]       + r*A1[HID+k]);
    v1[gid] = f2b(q*A1[2*HID+k] + r*A1[3*HID+k]);
}

// dst-centric forward: Hs (bf16) + ds[e][k] (bf16) + Sds[dst][k] = sum ds
__global__ __launch_bounds__(128) void k_edge_fwd_dst(
    const int* __restrict__ csr, const int* __restrict__ rptr, const int* __restrict__ cnt,
    const float* __restrict__ dgnn, const bf* __restrict__ u, const bf* __restrict__ v,
    const float* __restrict__ wdp, const float* __restrict__ bb,
    bf* __restrict__ Hs, bf* __restrict__ dsO, bf* __restrict__ Sds)
{
    __shared__ int ss[128]; __shared__ int se_[128]; __shared__ float sd[128];
    int dst = blockIdx.x, k = threadIdx.x;
    int n = cnt[dst], r0 = rptr[dst];
    if (k < n){ int e = csr[r0+k]; ss[k] = e>>4; se_[k] = e; sd[k] = dgnn[e]; }
    __syncthreads();
    float vk = b2f(v[dst*HID+k]), wd = wdp[k], bk = bb[k];
    float hsum = 0.f, dssum = 0.f;
    for (int j=0;j<n;j++){
        float a = b2f(u[ss[j]*HID+k]) + vk + sd[j]*wd + bk;
        float sg = sigf(a);
        hsum += a*sg;
        float dv = sg*(1.f + a*(1.f - sg));
        dssum += dv;
        dsO[(size_t)se_[j]*HID + k] = f2b(dv);
    }
    Hs[dst*HID+k] = f2b(hsum);
    Sds[dst*HID+k] = f2b(dssum);
}

// MFMA node forward: z = Hs@C + cnt*D ; x=silu(z) ; dsz=silu'(z) ; u=x@Aa ; v=x@Ab
__global__ __launch_bounds__(256) void k_node_fwd_uv_mfma(
    const short* __restrict__ Hs, const int* __restrict__ cnt,
    const short* __restrict__ Ct, const float* __restrict__ D,
    const short* __restrict__ Aat, const short* __restrict__ Abt,
    bf* __restrict__ dsz, bf* __restrict__ u, bf* __restrict__ v)
{
    __shared__ short sx[64*HID];
    int lane = threadIdx.x & 63, w = threadIdx.x >> 6;
    int m0 = blockIdx.x*64 + w*16;
    int ar = lane & 15, kg = lane >> 4;
    bf8v af[4];
#pragma unroll
    for (int s=0;s<4;s++) af[s] = *(const bf8v*)&Hs[(size_t)(m0+ar)*HID + s*32 + kg*8];
    f4v acc[8];
#pragma unroll
    for (int nt=0;nt<8;nt++){
        acc[nt] = (f4v){0.f,0.f,0.f,0.f};
        const short* bp = Ct + (nt*16+ar)*HID + kg*8;
#pragma unroll
        for (int s=0;s<4;s++){
            bf8v bv = *(const bf8v*)(bp + s*32);
            acc[nt] = __builtin_amdgcn_mfma_f32_16x16x32_bf16(af[s], bv, acc[nt], 0,0,0);
        }
    }
    float cn[4];
#pragma unroll
    for (int r=0;r<4;r++) cn[r] = (float)cnt[m0 + kg*4 + r];
#pragma unroll
    for (int nt=0;nt<8;nt++){
        int j = nt*16 + ar;
        float Dj = D[j];
#pragma unroll
        for (int r=0;r<4;r++){
            int m = m0 + kg*4 + r;
            float zv = acc[nt][r] + cn[r]*Dj;
            float sg = sigf(zv);
            dsz[(size_t)m*HID + j] = f2b(sg*(1.f + zv*(1.f - sg)));
            sx[(w*16 + kg*4 + r)*HID + j] = f2s(zv*sg);
        }
    }
    __syncthreads();
#pragma unroll
    for (int s=0;s<4;s++) af[s] = *(const bf8v*)&sx[(w*16+ar)*HID + s*32 + kg*8];
    f4v au[8], av[8];
#pragma unroll
    for (int nt=0;nt<8;nt++){
        au[nt] = (f4v){0.f,0.f,0.f,0.f};
        av[nt] = (f4v){0.f,0.f,0.f,0.f};
        const short* bpa = Aat + (nt*16+ar)*HID + kg*8;
        const short* bpb = Abt + (nt*16+ar)*HID + kg*8;
#pragma unroll
        for (int s=0;s<4;s++){
            bf8v ba = *(const bf8v*)(bpa + s*32);
            bf8v bb = *(const bf8v*)(bpb + s*32);
            au[nt] = __builtin_amdgcn_mfma_f32_16x16x32_bf16(af[s], ba, au[nt], 0,0,0);
            av[nt] = __builtin_amdgcn_mfma_f32_16x16x32_bf16(af[s], bb, av[nt], 0,0,0);
        }
    }
#pragma unroll
    for (int nt=0;nt<8;nt++){
        int j = nt*16 + ar;
#pragma unroll
        for (int r=0;r<4;r++){
            int m = m0 + kg*4 + r;
            u[(size_t)m*HID + j] = f2b(au[nt][r]);
            v[(size_t)m*HID + j] = f2b(av[nt][r]);
        }
    }
}

// MFMA node backward. If Sds != nullptr: Gd frag = gHin ⊙ Sds (not materialized).
__global__ __launch_bounds__(256) void k_gx_node_bwd_mfma(
    const short* __restrict__ Gs, const short* __restrict__ Gd,
    const short* __restrict__ gHin, const short* __restrict__ Sds,
    const short* __restrict__ Ra, const short* __restrict__ Rb,
    const bf* __restrict__ dsz, const short* __restrict__ Rc,
    bf* __restrict__ gHout)
{
    __shared__ short st[64*HID];
    int lane = threadIdx.x & 63, w = threadIdx.x >> 6;
    int m0 = blockIdx.x*64 + w*16;
    int ar = lane & 15, kg = lane >> 4;
    bf8v as_[4], ad_[4];
#pragma unroll
    for (int s=0;s<4;s++)
        as_[s] = *(const bf8v*)&Gs[(size_t)(m0+ar)*HID + s*32 + kg*8];
    if (Sds){
#pragma unroll
        for (int s=0;s<4;s++){
            bf8v g = *(const bf8v*)&gHin[(size_t)(m0+ar)*HID + s*32 + kg*8];
            bf8v sd = *(const bf8v*)&Sds[(size_t)(m0+ar)*HID + s*32 + kg*8];
            bf8v r;
#pragma unroll
            for (int i=0;i<8;i++) r[i] = f2s(s2f(g[i])*s2f(sd[i]));
            ad_[s] = r;
        }
    } else {
#pragma unroll
        for (int s=0;s<4;s++)
            ad_[s] = *(const bf8v*)&Gd[(size_t)(m0+ar)*HID + s*32 + kg*8];
    }
    f4v acc[8];
#pragma unroll
    for (int nt=0;nt<8;nt++){
        acc[nt] = (f4v){0.f,0.f,0.f,0.f};
        const short* bpa = Ra + (nt*16+ar)*HID + kg*8;
        const short* bpb = Rb + (nt*16+ar)*HID + kg*8;
#pragma unroll
        for (int s=0;s<4;s++){
            bf8v ba = *(const bf8v*)(bpa + s*32);
            bf8v bb = *(const bf8v*)(bpb + s*32);
            acc[nt] = __builtin_amdgcn_mfma_f32_16x16x32_bf16(as_[s], ba, acc[nt], 0,0,0);
            acc[nt] = __builtin_amdgcn_mfma_f32_16x16x32_bf16(ad_[s], bb, acc[nt], 0,0,0);
        }
    }
#pragma unroll
    for (int nt=0;nt<8;nt++){
        int j = nt*16 + ar;
#pragma unroll
        for (int r=0;r<4;r++){
            int m = m0 + kg*4 + r;
            float t = acc[nt][r] * b2f(dsz[(size_t)m*HID + j]);
            st[(w*16 + kg*4 + r)*HID + j] = f2s(t);
        }
    }
    __syncthreads();
    bf8v af[4];
#pragma unroll
    for (int s=0;s<4;s++) af[s] = *(const bf8v*)&st[(w*16+ar)*HID + s*32 + kg*8];
    f4v a2[8];
#pragma unroll
    for (int nt=0;nt<8;nt++){
        a2[nt] = (f4v){0.f,0.f,0.f,0.f};
        const short* bp = Rc + (nt*16+ar)*HID + kg*8;
#pragma unroll
        for (int s=0;s<4;s++){
            bf8v bc = *(const bf8v*)(bp + s*32);
            a2[nt] = __builtin_amdgcn_mfma_f32_16x16x32_bf16(af[s], bc, a2[nt], 0,0,0);
        }
    }
#pragma unroll
    for (int nt=0;nt<8;nt++){
        int j = nt*16 + ar;
#pragma unroll
        for (int r=0;r<4;r++){
            gHout[(size_t)(m0 + kg*4 + r)*HID + j] = f2b(a2[nt][r]);
        }
    }
}

// l3 dst pass: computes a once; writes ds3[e], Gd3 (bf16), x3
__global__ __launch_bounds__(128) void k_l3_dst(
    const int* __restrict__ csr, const int* __restrict__ rptr, const int* __restrict__ cnt,
    const float* __restrict__ dgnn, const bf* __restrict__ u, const bf* __restrict__ v,
    const float* __restrict__ A3, const float* __restrict__ B3,
    const float* __restrict__ C3, const float* __restrict__ D3,
    bf* __restrict__ ds3, bf* __restrict__ Gd, float* __restrict__ x3)
{
    __shared__ int ss[128]; __shared__ int se_[128]; __shared__ float sd[128];
    __shared__ float rr[2];
    int dst = blockIdx.x, k = threadIdx.x;
    int n = cnt[dst], r0 = rptr[dst];
    if (k < n){ int e = csr[r0+k]; ss[k] = e>>4; se_[k] = e; sd[k] = dgnn[e]; }
    __syncthreads();
    float vk = b2f(v[dst*HID+k]), wd = A3[256*HID+k], bk = B3[k], ck = C3[k];
    float hsum = 0.f, dssum = 0.f;
    for (int j=0;j<n;j++){
        float a = b2f(u[ss[j]*HID+k]) + vk + sd[j]*wd + bk;
        float sg = sigf(a);
        hsum += a*sg;
        float dv = sg*(1.f + a*(1.f - sg));
        dssum += dv;
        ds3[(size_t)se_[j]*HID + k] = f2b(dv);
    }
    Gd[dst*HID+k] = f2b(ck*dssum);
    float pv = waveRed(ck*hsum);
    if ((k&63)==0) rr[k>>6] = pv;
    __syncthreads();
    if (k==0) x3[dst] = rr[0] + rr[1] + (float)n*D3[0];
}

// l3 src pass: LDS-staged contiguous ds3 slab -> Gs3 + gdg (=)
__global__ __launch_bounds__(128) void k_l3_src(
    const bf* __restrict__ ds3,
    const float* __restrict__ A3, const float* __restrict__ C3,
    bf* __restrict__ Gs, float* __restrict__ gdg)
{
    __shared__ short sds[2048];
    __shared__ float sQ[16][130];
    int s = blockIdx.x, k = threadIdx.x;
    const bf8v* slab = (const bf8v*)((const short*)ds3 + (size_t)s*2048);
    ((bf8v*)sds)[k]     = slab[k];
    ((bf8v*)sds)[128+k] = slab[128+k];
    __syncthreads();
    float wd = A3[256*HID+k], ck = C3[k];
    float cw = ck*wd;
    float gs = 0.f;
#pragma unroll
    for (int t=0;t<16;t++){
        float dv = s2f(sds[t*128+k]);
        gs += dv;
        sQ[t][k] = dv*cw;
    }
    Gs[s*HID+k] = f2b(ck*gs);
    __syncthreads();
    int t = k >> 3, r = k & 7;
    float pg = 0.f;
#pragma unroll
    for (int i=0;i<16;i++) pg += sQ[t][i + 16*r];
    pg += __shfl_xor(pg,1); pg += __shfl_xor(pg,2); pg += __shfl_xor(pg,4);
    if (r==0) gdg[s*16+t] = pg;
}

// layer-2 bwd src-only: LDS-staged ds2 slab + gH rows -> Gs2 + gdg +=
__global__ __launch_bounds__(128) void k_bwd_src(
    const int* __restrict__ gei, const bf* __restrict__ ds2,
    const float* __restrict__ wdp, const bf* __restrict__ gH,
    bf* __restrict__ Gs, float* __restrict__ gdg)
{
    __shared__ short sds[2048];
    __shared__ short sgh[2048];
    __shared__ float sQ[16][130];
    int s = blockIdx.x, k = threadIdx.x;
    const bf8v* slab = (const bf8v*)((const short*)ds2 + (size_t)s*2048);
    ((bf8v*)sds)[k]     = slab[k];
    ((bf8v*)sds)[128+k] = slab[128+k];
    {
        int t = k >> 3, q = k & 7;
        int dst = gei[EGNN + s*16 + t];
        const bf8v* gr = (const bf8v*)((const short*)gH + (size_t)dst*HID);
        ((bf8v*)sgh)[t*16 + q*2]     = gr[q*2];
        ((bf8v*)sgh)[t*16 + q*2 + 1] = gr[q*2+1];
    }
    __syncthreads();
    float wd = wdp[k];
    float gs = 0.f;
#pragma unroll
    for (int t=0;t<16;t++){
        float ga = s2f(sgh[t*128+k]) * s2f(sds[t*128+k]);
        gs += ga;
        sQ[t][k] = ga*wd;
    }
    Gs[s*HID+k] = f2b(gs);
    __syncthreads();
    int t = k >> 3, r = k & 7;
    float pg = 0.f;
#pragma unroll
    for (int i=0;i<16;i++) pg += sQ[t][i + 16*r];
    pg += __shfl_xor(pg,1); pg += __shfl_xor(pg,2); pg += __shfl_xor(pg,4);
    if (r==0) gdg[s*16+t] += pg;
}

// layer-1 bwd: LDS-staged ds1 slab + gH rows -> gdg +=
__global__ __launch_bounds__(128) void k_bwd1_src(
    const int* __restrict__ gei, const bf* __restrict__ ds1,
    const float* __restrict__ wdp, const bf* __restrict__ gH,
    float* __restrict__ gdg)
{
    __shared__ short sds[2048];
    __shared__ short sgh[2048];
    __shared__ float sQ[16][130];
    int s = blockIdx.x, k = threadIdx.x;
    const bf8v* slab = (const bf8v*)((const short*)ds1 + (size_t)s*2048);
    ((bf8v*)sds)[k]     = slab[k];
    ((bf8v*)sds)[128+k] = slab[128+k];
    {
        int t = k >> 3, q = k & 7;
        int dst = gei[EGNN + s*16 + t];
        const bf8v* gr = (const bf8v*)((const short*)gH + (size_t)dst*HID);
        ((bf8v*)sgh)[t*16 + q*2]     = gr[q*2];
        ((bf8v*)sgh)[t*16 + q*2 + 1] = gr[q*2+1];
    }
    __syncthreads();
    float wd = wdp[k];
#pragma unroll
    for (int t=0;t<16;t++){
        float ga = s2f(sgh[t*128+k]) * s2f(sds[t*128+k]);
        sQ[t][k] = ga*wd;
    }
    __syncthreads();
    int t = k >> 3, r = k & 7;
    float pg = 0.f;
#pragma unroll
    for (int i=0;i<16;i++) pg += sQ[t][i + 16*r];
    pg += __shfl_xor(pg,1); pg += __shfl_xor(pg,2); pg += __shfl_xor(pg,4);
    if (r==0) gdg[s*16+t] += pg;
}

__global__ __launch_bounds__(256) void k_force_atom(
    const float* __restrict__ pos, const int* __restrict__ gei,
    const int* __restrict__ csr, const int* __restrict__ rptr, const int* __restrict__ cnt,
    const float* __restrict__ dgnn, const float* __restrict__ gdg,
    float* __restrict__ grad)
{
    int T = blockIdx.x*256 + threadIdx.x;
    int i = T >> 3, p = T & 7;
    float px = pos[3*i+0], py = pos[3*i+1], pz = pos[3*i+2];
    float ax=0.f, ay=0.f, az=0.f;
    for (int j=p;j<16;j+=8){
        int e = i*16 + j;
        int o = gei[EGNN+e];
        float c = gdg[e]/dgnn[e];
        ax += c*(px - pos[3*o+0]);
        ay += c*(py - pos[3*o+1]);
        az += c*(pz - pos[3*o+2]);
    }
    int n = cnt[i], r0 = rptr[i];
    for (int j=p;j<n;j+=8){
        int e = csr[r0+j];
        int o = e >> 4;
        float c = gdg[e]/dgnn[e];
        ax += c*(px - pos[3*o+0]);
        ay += c*(py - pos[3*o+1]);
        az += c*(pz - pos[3*o+2]);
    }
    ax += __shfl_xor(ax,1); ax += __shfl_xor(ax,2); ax += __shfl_xor(ax,4);
    ay += __shfl_xor(ay,1); ay += __shfl_xor(ay,2); ay += __shfl_xor(ay,4);
    az += __shfl_xor(az,1); az += __shfl_xor(az,2); az += __shfl_xor(az,4);
    if (p==0){
        grad[3*i+0] += ax;
        grad[3*i+1] += ay;
        grad[3*i+2] += az;
    }
}

__global__ __launch_bounds__(256) void k_final(
    const float* __restrict__ egb, const float* __restrict__ x3,
    const float* __restrict__ grad, float* __restrict__ out)
{
    __shared__ float red[4];
    int m = blockIdx.x, tid = threadIdx.x;
    int i = m*ATOMSM + tid;
    float en = egb[i] + x3[i];
    float v = waveRed(en);
    int wave = tid>>6, lane = tid&63;
    if (lane==0) red[wave] = v;
    __syncthreads();
    if (tid==0) out[m] = red[0]+red[1]+red[2]+red[3];
    float* f = out + MOLS;
    f[3*i+0] = -grad[3*i+0];
    f[3*i+1] = -grad[3*i+1];
    f[3*i+2] = -grad[3*i+2];
}

extern "C" void kernel_launch(void* const* d_in, const int* in_sizes, int n_in,
                              void* d_out, int out_size, void* d_ws, size_t ws_size,
                              hipStream_t stream)
{
    const float* pos  = (const float*)d_in[0];
    const float* feat = (const float*)d_in[1];
    const int* ei  = (const int*)d_in[3];
    const int* gei = (const int*)d_in[4];
    const float* A1f = (const float*)d_in[5];  const float* B1f = (const float*)d_in[6];
    const float* C1f = (const float*)d_in[7];  const float* D1f = (const float*)d_in[8];
    const float* A2f = (const float*)d_in[9];  const float* B2f = (const float*)d_in[10];
    const float* C2f = (const float*)d_in[11]; const float* D2f = (const float*)d_in[12];
    const float* A3f = (const float*)d_in[13]; const float* B3f = (const float*)d_in[14];
    const float* C3f = (const float*)d_in[15]; const float* D3f = (const float*)d_in[16];

    float* w = (float*)d_ws;
    size_t off = 0;
    auto nxt = [&](size_t n)->float*{ float* p = w + off; off += (n + 255) & ~(size_t)255; return p; };
    float* Isum = nxt(NATOMS); float* Bv = nxt(NATOMS); float* cB = nxt(NATOMS);
    float* gB = nxt(NATOMS); float* egb = nxt(NATOMS); float* x3 = nxt(NATOMS);
    int*   cnt  = (int*)nxt(NATOMS);
    int*   rptr = (int*)nxt(NATOMS);
    int*   curs = (int*)nxt(NATOMS);
    int*   csr  = (int*)nxt(EGNN);
    float* dgnn = nxt(EGNN); float* gdgnn = nxt(EGNN); float* gdgb = nxt(EGB);
    float* grad = nxt(3*NATOMS);
    bf* dsz1 = (bf*)nxt(NH/2); bf* dsz2 = (bf*)nxt(NH/2);
    bf* Hs1 = (bf*)nxt(NH/2); bf* Hs2 = (bf*)nxt(NH/2);
    bf* Gs3 = (bf*)nxt(NH/2); bf* Gd3 = (bf*)nxt(NH/2);
    bf* Sds2 = (bf*)nxt(NH/2);
    bf* u1 = (bf*)nxt(NH/2); bf* v1 = (bf*)nxt(NH/2);
    bf* u2 = (bf*)nxt(NH/2); bf* v2 = (bf*)nxt(NH/2);
    bf* v3 = (bf*)nxt(NH/2);
    short* C1t  = (short*)nxt(8192); short* C2t  = (short*)nxt(8192);
    short* A2at = (short*)nxt(8192); short* A2bt = (short*)nxt(8192);
    short* A3at = (short*)nxt(8192); short* A3bt = (short*)nxt(8192);
    short* rA2a = (short*)nxt(8192); short* rA2b = (short*)nxt(8192);
    short* rA3a = (short*)nxt(8192); short* rA3b = (short*)nxt(8192);
    short* rC1  = (short*)nxt(8192); short* rC2  = (short*)nxt(8192);
    bf* ds1 = (bf*)nxt((size_t)EGNN*HID/2);
    bf* ds2 = (bf*)nxt((size_t)EGNN*HID/2);
    bf* ds3 = (bf*)nxt((size_t)EGNN*HID/2);
    // aliases:
    bf* u3  = Hs1;      // Hs1 dead after node_fwd #1
    bf* gH2 = Hs2;      // Hs2 dead after node_fwd #2
    bf* Gs2 = Gs3;      // dead after gx_node_bwd(3->2)
    bf* gH1 = u3;       // u3 dead after l3_dst

    hipMemsetAsync(Isum, 0, NATOMS*sizeof(float), stream);
    hipMemsetAsync(cnt,  0, NATOMS*sizeof(int), stream);
    hipMemsetAsync(grad, 0, 3*NATOMS*sizeof(float), stream);

    k_wprep<<<64,256,0,stream>>>(A2f, C1f, A3f, C2f,
        C1t, C2t, A2at, A2bt, A3at, A3bt, rA2a, rA2b, rA3a, rA3b, rC1, rC2);

    // GB chain
    k_gbA<<<512,256,0,stream>>>(pos, feat, ei, Isum);
    k_gbB<<<NATOMS/256,256,0,stream>>>(feat, Isum, Bv, cB, gB, egb);
    k_gbC<<<512,256,0,stream>>>(pos, feat, ei, Bv, egb, gdgb, gB);
    k_gbD<<<NATOMS/256,256,0,stream>>>(gB, cB);
    k_gbE<<<512,256,0,stream>>>(pos, feat, ei, cB, gdgb, grad);

    // dist + CSR build
    k_dist<<<EGNN/256,256,0,stream>>>(pos, gei, dgnn, cnt);
    k_scan<<<MOLS,256,0,stream>>>(cnt, rptr, curs);
    k_fill<<<EGNN/256,256,0,stream>>>(gei, curs, csr);

    // forward (silu' caching + per-dst silu' sums)
    k_uv1<<<NH/256,256,0,stream>>>(feat, A1f, u1, v1);
    k_edge_fwd_dst<<<NATOMS,128,0,stream>>>(csr, rptr, cnt, dgnn, u1, v1,
                                            A1f+4*HID, B1f, Hs1, ds1, Sds2 /*garbage, overwritten*/);
    k_node_fwd_uv_mfma<<<NATOMS/64,256,0,stream>>>((const short*)Hs1, cnt, C1t, D1f,
                                                   A2at, A2bt, dsz1, u2, v2);
    k_edge_fwd_dst<<<NATOMS,128,0,stream>>>(csr, rptr, cnt, dgnn, u2, v2,
                                            A2f+256*HID, B2f, Hs2, ds2, Sds2);
    k_node_fwd_uv_mfma<<<NATOMS/64,256,0,stream>>>((const short*)Hs2, cnt, C2t, D2f,
                                                   A3at, A3bt, dsz2, u3, v3);

    // layer-3: dst (compute+cache) then src (stream)
    k_l3_dst<<<NATOMS,128,0,stream>>>(csr, rptr, cnt, dgnn, u3, v3,
                                      A3f, B3f, C3f, D3f, ds3, Gd3, x3);
    k_l3_src<<<NATOMS,128,0,stream>>>(ds3, A3f, C3f, Gs3, gdgnn);

    // backward chain
    k_gx_node_bwd_mfma<<<NATOMS/64,256,0,stream>>>((const short*)Gs3, (const short*)Gd3,
        (const short*)nullptr, (const short*)nullptr, rA3a, rA3b, dsz2, rC2, gH2);
    k_bwd_src<<<NATOMS,128,0,stream>>>(gei, ds2, A2f+256*HID, gH2, Gs2, gdgnn);
    k_gx_node_bwd_mfma<<<NATOMS/64,256,0,stream>>>((const short*)Gs2, (const short*)nullptr,
        (const short*)gH2, (const short*)Sds2, rA2a, rA2b, dsz1, rC1, gH1);
    k_bwd1_src<<<NATOMS,128,0,stream>>>(gei, ds1, A1f+4*HID, gH1, gdgnn);
    k_force_atom<<<NATOMS*8/256,256,0,stream>>>(pos, gei, csr, rptr, cnt, dgnn, gdgnn, grad);

    k_final<<<MOLS,256,0,stream>>>(egb, x3, grad, (float*)d_out);
}

// Round 12
// 392.112 us; speedup vs baseline: 1.1109x; 1.0266x over previous
//
#include <hip/hip_runtime.h>
#include <hip/hip_bf16.h>

#define NATOMS 16384
#define MOLS   64
#define ATOMSM 256
#define EGB    524288
#define EGNN   262144
#define HID    128
#define NH     (NATOMS*HID)

#define OFFSETC 0.009f
#define ALPHAC  1.0f
#define BETAC   0.8f
#define GAMMAC  4.85f
#define PREFC   (-138.935456f*(1.0f-1.0f/78.5f))

typedef __hip_bfloat16 bf;
typedef __attribute__((ext_vector_type(8))) short bf8v;
typedef __attribute__((ext_vector_type(4))) float f4v;

__device__ __forceinline__ float b2f(bf x){ return __bfloat162float(x); }
__device__ __forceinline__ bf f2b(float x){ return __float2bfloat16(x); }
__device__ __forceinline__ short f2s(float x){ bf h = f2b(x); return *(short*)&h; }
__device__ __forceinline__ float s2f(short s){
    unsigned int x = ((unsigned int)(unsigned short)s) << 16;
    return __uint_as_float(x);
}
__device__ __forceinline__ float sigf(float x){ return 1.0f/(1.0f+__expf(-x)); }
__device__ __forceinline__ float waveRed(float v){
    v += __shfl_xor(v,32); v += __shfl_xor(v,16); v += __shfl_xor(v,8);
    v += __shfl_xor(v,4);  v += __shfl_xor(v,2);  v += __shfl_xor(v,1);
    return v;
}

// ============ GB: LDS molecule-tile staged, gathers from LDS ============
__global__ __launch_bounds__(256) void k_gbA(
    const float* __restrict__ pos, const float* __restrict__ feat,
    const int* __restrict__ ei, float* __restrict__ Isum)
{
    __shared__ float sPx[256], sPy[256], sPz[256], sRho[256], sSr[256];
    __shared__ float sI[256];
    int tid = threadIdx.x;
    int mbase = (blockIdx.x >> 3) * 256;
    {
        int i = mbase + tid;
        sPx[tid]=pos[3*i]; sPy[tid]=pos[3*i+1]; sPz[tid]=pos[3*i+2];
        float rad = feat[7*i+1], sc = feat[7*i+2];
        float rho = rad - OFFSETC;
        sRho[tid]=rho; sSr[tid]=sc*rho;
        sI[tid]=0.f;
    }
    __syncthreads();
    int T = blockIdx.x*256 + tid;
    int s = T >> 3, p = T & 7;
    int sl = s & 255;
    int e0 = s*32 + p*4;
    float px = sPx[sl], py = sPy[sl], pz = sPz[sl];
    float sr = sSr[sl];
    const int* dP = ei + EGB;
#pragma unroll
    for (int j=0;j<4;j++){
        int dl = dP[e0+j] & 255;
        float dx = px - sPx[dl];
        float dy = py - sPy[dl];
        float dz = pz - sPz[dl];
        float d  = sqrtf(dx*dx+dy*dy+dz*dz + 1e-12f);
        float rho_i = sRho[dl];
        float U = d + sr;
        if (rho_i < U){
            float L = fmaxf(rho_i, fabsf(d - sr));
            float invU = 1.0f/U, invL = 1.0f/L;
            float I = 0.5f*invL - 0.5f*invU
                    + 0.125f*(d - sr*sr/d)*(invU*invU - invL*invL)
                    + 0.25f*__logf(L*invU)/d;
            atomicAdd(&sI[dl], I);
        }
    }
    __syncthreads();
    atomicAdd(&Isum[mbase + tid], sI[tid]);
}

__global__ __launch_bounds__(256) void k_gbB(
    const float* __restrict__ feat, const float* __restrict__ Isum,
    float* __restrict__ Bv, float* __restrict__ cB, float* __restrict__ gB,
    float* __restrict__ egb)
{
    int i = blockIdx.x*256 + threadIdx.x;
    if (i >= NATOMS) return;
    float q   = feat[7*i+0];
    float rad = feat[7*i+1];
    float rho = rad - OFFSETC;
    float psi = Isum[i]*rho;
    float u = psi*(ALPHAC + psi*(-BETAC + GAMMAC*psi));
    float t = tanhf(u);
    float B = 1.0f/(1.0f/rho - t/rad);
    Bv[i] = B;
    float du = ALPHAC + psi*(-2.0f*BETAC + 3.0f*GAMMAC*psi);
    cB[i] = B*B*((1.0f-t*t)/rad)*du*rho;
    float Cs = 0.5f*PREFC*q*q;
    egb[i] = Cs/B;
    gB[i]  = -Cs/(B*B);
}

__global__ __launch_bounds__(256) void k_gbC(
    const float* __restrict__ pos, const float* __restrict__ feat,
    const int* __restrict__ ei, const float* __restrict__ Bv,
    float* __restrict__ egb, float* __restrict__ gdgb, float* __restrict__ gB)
{
    __shared__ float sPx[256], sPy[256], sPz[256], sB[256], sQf[256];
    __shared__ float sE[256], sG[256];
    int tid = threadIdx.x;
    int mbase = (blockIdx.x >> 3) * 256;
    {
        int i = mbase + tid;
        sPx[tid]=pos[3*i]; sPy[tid]=pos[3*i+1]; sPz[tid]=pos[3*i+2];
        sB[tid]=Bv[i]; sQf[tid]=feat[7*i+0];
        sE[tid]=0.f; sG[tid]=0.f;
    }
    __syncthreads();
    int T = blockIdx.x*256 + tid;
    int s = T >> 3, p = T & 7;
    int sl = s & 255;
    int e0 = s*32 + p*4;
    float px = sPx[sl], py = sPy[sl], pz = sPz[sl];
    float qs = sQf[sl];
    float Bs = sB[sl];
    float gsrc = 0.f;
    const int* dP = ei + EGB;
#pragma unroll
    for (int j=0;j<4;j++){
        int dl = dP[e0+j] & 255;
        float dx = px - sPx[dl];
        float dy = py - sPy[dl];
        float dz = pz - sPz[dl];
        float d2 = dx*dx+dy*dy+dz*dz + 1e-12f;
        float d  = sqrtf(d2);
        float Bd = sB[dl];
        float C = 0.5f*PREFC*sQf[dl]*qs;
        float P = Bd*Bs;
        float ex = __expf(-d2/(4.f*P));
        float f2 = d2 + P*ex;
        float f  = sqrtf(f2);
        float f3i = 1.f/(f2*f);
        gdgb[e0+j] = -C*d*(1.f - 0.25f*ex)*f3i;
        float common = -C*ex*(1.f + d2/(4.f*P))*0.5f*f3i;
        atomicAdd(&sE[dl], C/f);
        atomicAdd(&sG[dl], common*Bs);
        gsrc += common*Bd;
    }
    gsrc += __shfl_xor(gsrc,1);
    gsrc += __shfl_xor(gsrc,2);
    gsrc += __shfl_xor(gsrc,4);
    if (p==0) atomicAdd(&sG[sl], gsrc);
    __syncthreads();
    atomicAdd(&egb[mbase + tid], sE[tid]);
    atomicAdd(&gB[mbase + tid],  sG[tid]);
}

// gbE with gbD fused: cBg = cB*gB computed at staging
__global__ __launch_bounds__(256) void k_gbE(
    const float* __restrict__ pos, const float* __restrict__ feat,
    const int* __restrict__ ei, const float* __restrict__ cB,
    const float* __restrict__ gB,
    const float* __restrict__ gdgb, float* __restrict__ grad)
{
    __shared__ float sPx[256], sPy[256], sPz[256], sRho[256], sSr[256], sCg[256];
    __shared__ float sGx[256], sGy[256], sGz[256];
    int tid = threadIdx.x;
    int mbase = (blockIdx.x >> 3) * 256;
    {
        int i = mbase + tid;
        sPx[tid]=pos[3*i]; sPy[tid]=pos[3*i+1]; sPz[tid]=pos[3*i+2];
        float rad = feat[7*i+1], sc = feat[7*i+2];
        float rho = rad - OFFSETC;
        sRho[tid]=rho; sSr[tid]=sc*rho;
        sCg[tid]=cB[i]*gB[i];
        sGx[tid]=0.f; sGy[tid]=0.f; sGz[tid]=0.f;
    }
    __syncthreads();
    int T = blockIdx.x*256 + tid;
    int s = T >> 3, p = T & 7;
    int sl = s & 255;
    int e0 = s*32 + p*4;
    float px = sPx[sl], py = sPy[sl], pz = sPz[sl];
    float sr = sSr[sl];
    float gx=0.f, gy=0.f, gz=0.f;
    const int* dP = ei + EGB;
#pragma unroll
    for (int j=0;j<4;j++){
        int dl = dP[e0+j] & 255;
        float dx = px - sPx[dl];
        float dy = py - sPy[dl];
        float dz = pz - sPz[dl];
        float d2 = dx*dx+dy*dy+dz*dz + 1e-12f;
        float d  = sqrtf(d2);
        float rho_i = sRho[dl];
        float U = d + sr;
        float gd = gdgb[e0+j];
        if (rho_i < U){
            float aa = fabsf(d - sr);
            float L, Lp;
            if (rho_i >= aa){ L = rho_i; Lp = 0.f; }
            else { L = aa; Lp = (d >= sr) ? 1.f : -1.f; }
            float invU = 1.f/U, invL = 1.f/L;
            float invU2=invU*invU, invL2=invL*invL;
            float dIdd = -0.5f*Lp*invL2 + 0.5f*invU2
                + 0.125f*(1.f + sr*sr/d2)*(invU2 - invL2)
                + 0.125f*(d - sr*sr/d)*(2.f*Lp*invL2*invL - 2.f*invU2*invU)
                + 0.25f*((Lp*invL - invU)/d - __logf(L*invU)/d2);
            gd += sCg[dl]*dIdd;
        }
        float c = gd/d;
        gx += c*dx; gy += c*dy; gz += c*dz;
        atomicAdd(&sGx[dl], -c*dx);
        atomicAdd(&sGy[dl], -c*dy);
        atomicAdd(&sGz[dl], -c*dz);
    }
    gx += __shfl_xor(gx,1); gx += __shfl_xor(gx,2); gx += __shfl_xor(gx,4);
    gy += __shfl_xor(gy,1); gy += __shfl_xor(gy,2); gy += __shfl_xor(gy,4);
    gz += __shfl_xor(gz,1); gz += __shfl_xor(gz,2); gz += __shfl_xor(gz,4);
    if (p==0){
        atomicAdd(&sGx[sl], gx);
        atomicAdd(&sGy[sl], gy);
        atomicAdd(&sGz[sl], gz);
    }
    __syncthreads();
    int i = mbase + tid;
    atomicAdd(&grad[3*i+0], sGx[tid]);
    atomicAdd(&grad[3*i+1], sGy[tid]);
    atomicAdd(&grad[3*i+2], sGz[tid]);
}

// ---------------- GNN: dist + CSR build ----------------
__global__ __launch_bounds__(256) void k_dist(
    const float* __restrict__ pos, const int* __restrict__ gei,
    float* __restrict__ dgnn, int* __restrict__ cnt)
{
    int e = blockIdx.x*256 + threadIdx.x;
    if (e >= EGNN) return;
    int s = gei[e], dd = gei[EGNN+e];
    float dx = pos[3*s+0] - pos[3*dd+0];
    float dy = pos[3*s+1] - pos[3*dd+1];
    float dz = pos[3*s+2] - pos[3*dd+2];
    dgnn[e] = sqrtf(dx*dx+dy*dy+dz*dz + 1e-12f);
    atomicAdd(&cnt[dd], 1);
}

__global__ __launch_bounds__(256) void k_scan(
    const int* __restrict__ cnt, int* __restrict__ rptr, int* __restrict__ cursor)
{
    __shared__ int sc[256];
    int m = blockIdx.x, t = threadIdx.x;
    int c = cnt[m*256+t];
    sc[t] = c; __syncthreads();
    for (int off=1; off<256; off<<=1){
        int x = (t>=off) ? sc[t-off] : 0;
        __syncthreads();
        sc[t] += x;
        __syncthreads();
    }
    int ex = m*4096 + sc[t] - c;
    rptr[m*256+t] = ex;
    cursor[m*256+t] = ex;
}

__global__ __launch_bounds__(256) void k_fill(
    const int* __restrict__ gei, int* __restrict__ cursor, int* __restrict__ csr)
{
    int e = blockIdx.x*256 + threadIdx.x;
    if (e >= EGNN) return;
    int dst = gei[EGNN+e];
    int pos = atomicAdd(&cursor[dst], 1);
    csr[pos] = e;
}

// ---------------- weight prep ----------------
__global__ __launch_bounds__(256) void k_wprep(
    const float* __restrict__ A2, const float* __restrict__ C1,
    const float* __restrict__ A3, const float* __restrict__ C2,
    short* __restrict__ C1t, short* __restrict__ C2t,
    short* __restrict__ A2at, short* __restrict__ A2bt,
    short* __restrict__ A3at, short* __restrict__ A3bt,
    short* __restrict__ rA2a, short* __restrict__ rA2b,
    short* __restrict__ rA3a, short* __restrict__ rA3b,
    short* __restrict__ rC1, short* __restrict__ rC2)
{
    int gid = blockIdx.x*256 + threadIdx.x;
    int j = gid >> 7, k = gid & 127;
    C1t[gid]  = f2s(C1[k*HID+j]);
    C2t[gid]  = f2s(C2[k*HID+j]);
    A2at[gid] = f2s(A2[k*HID+j]);
    A2bt[gid] = f2s(A2[(HID+k)*HID+j]);
    A3at[gid] = f2s(A3[k*HID+j]);
    A3bt[gid] = f2s(A3[(HID+k)*HID+j]);
    rA2a[gid] = f2s(A2[gid]);
    rA2b[gid] = f2s(A2[HID*HID+gid]);
    rA3a[gid] = f2s(A3[gid]);
    rA3b[gid] = f2s(A3[HID*HID+gid]);
    rC1[gid]  = f2s(C1[gid]);
    rC2[gid]  = f2s(C2[gid]);
}

// ---------------- GNN compute ----------------
__global__ __launch_bounds__(256) void k_uv1(
    const float* __restrict__ feat, const float* __restrict__ A1,
    bf* __restrict__ u1, bf* __restrict__ v1)
{
    int gid = blockIdx.x*256 + threadIdx.x;
    int i = gid >> 7, k = gid & 127;
    float q = feat[7*i+0], r = feat[7*i+1];
    u1[gid] = f2b(q*A1[k]       + r*A1[HID+k]);
    v1[gid] = f2b(q*A1[2*HID+k] + r*A1[3*HID+k]);
}

// dst-centric forward, scalar-uniform metadata (no LDS staging)
__global__ __launch_bounds__(128) void k_edge_fwd_dst(
    const int* __restrict__ csr, const int* __restrict__ rptr, const int* __restrict__ cnt,
    const float* __restrict__ dgnn, const bf* __restrict__ u, const bf* __restrict__ v,
    const float* __restrict__ wdp, const float* __restrict__ bb,
    bf* __restrict__ Hs, bf* __restrict__ dsO, bf* __restrict__ Sds)
{
    int dst = blockIdx.x, k = threadIdx.x;
    int n = cnt[dst], r0 = rptr[dst];
    float wd = wdp[k];
    float base = b2f(v[dst*HID+k]) + bb[k];
    float hsum = 0.f, dssum = 0.f;
    const short* us = (const short*)u;
    short* dso = (short*)dsO;
#pragma unroll 2
    for (int j=0;j<n;j++){
        int e = csr[r0+j];
        float a = s2f(us[(size_t)(e>>4)*HID + k]) + base + dgnn[e]*wd;
        float sg = sigf(a);
        hsum += a*sg;
        float dv = sg*(1.f + a*(1.f - sg));
        dssum += dv;
        dso[(size_t)e*HID + k] = f2s(dv);
    }
    Hs[dst*HID+k] = f2b(hsum);
    Sds[dst*HID+k] = f2b(dssum);
}

// MFMA node forward
__global__ __launch_bounds__(256) void k_node_fwd_uv_mfma(
    const short* __restrict__ Hs, const int* __restrict__ cnt,
    const short* __restrict__ Ct, const float* __restrict__ D,
    const short* __restrict__ Aat, const short* __restrict__ Abt,
    bf* __restrict__ dsz, bf* __restrict__ u, bf* __restrict__ v)
{
    __shared__ short sx[64*HID];
    int lane = threadIdx.x & 63, w = threadIdx.x >> 6;
    int m0 = blockIdx.x*64 + w*16;
    int ar = lane & 15, kg = lane >> 4;
    bf8v af[4];
#pragma unroll
    for (int s=0;s<4;s++) af[s] = *(const bf8v*)&Hs[(size_t)(m0+ar)*HID + s*32 + kg*8];
    f4v acc[8];
#pragma unroll
    for (int nt=0;nt<8;nt++){
        acc[nt] = (f4v){0.f,0.f,0.f,0.f};
        const short* bp = Ct + (nt*16+ar)*HID + kg*8;
#pragma unroll
        for (int s=0;s<4;s++){
            bf8v bv = *(const bf8v*)(bp + s*32);
            acc[nt] = __builtin_amdgcn_mfma_f32_16x16x32_bf16(af[s], bv, acc[nt], 0,0,0);
        }
    }
    float cn[4];
#pragma unroll
    for (int r=0;r<4;r++) cn[r] = (float)cnt[m0 + kg*4 + r];
#pragma unroll
    for (int nt=0;nt<8;nt++){
        int j = nt*16 + ar;
        float Dj = D[j];
#pragma unroll
        for (int r=0;r<4;r++){
            int m = m0 + kg*4 + r;
            float zv = acc[nt][r] + cn[r]*Dj;
            float sg = sigf(zv);
            dsz[(size_t)m*HID + j] = f2b(sg*(1.f + zv*(1.f - sg)));
            sx[(w*16 + kg*4 + r)*HID + j] = f2s(zv*sg);
        }
    }
    __syncthreads();
#pragma unroll
    for (int s=0;s<4;s++) af[s] = *(const bf8v*)&sx[(w*16+ar)*HID + s*32 + kg*8];
    f4v au[8], av[8];
#pragma unroll
    for (int nt=0;nt<8;nt++){
        au[nt] = (f4v){0.f,0.f,0.f,0.f};
        av[nt] = (f4v){0.f,0.f,0.f,0.f};
        const short* bpa = Aat + (nt*16+ar)*HID + kg*8;
        const short* bpb = Abt + (nt*16+ar)*HID + kg*8;
#pragma unroll
        for (int s=0;s<4;s++){
            bf8v ba = *(const bf8v*)(bpa + s*32);
            bf8v bb = *(const bf8v*)(bpb + s*32);
            au[nt] = __builtin_amdgcn_mfma_f32_16x16x32_bf16(af[s], ba, au[nt], 0,0,0);
            av[nt] = __builtin_amdgcn_mfma_f32_16x16x32_bf16(af[s], bb, av[nt], 0,0,0);
        }
    }
#pragma unroll
    for (int nt=0;nt<8;nt++){
        int j = nt*16 + ar;
#pragma unroll
        for (int r=0;r<4;r++){
            int m = m0 + kg*4 + r;
            u[(size_t)m*HID + j] = f2b(au[nt][r]);
            v[(size_t)m*HID + j] = f2b(av[nt][r]);
        }
    }
}

// MFMA node backward. If Sds != nullptr: Gd frag = gHin ⊙ Sds.
__global__ __launch_bounds__(256) void k_gx_node_bwd_mfma(
    const short* __restrict__ Gs, const short* __restrict__ Gd,
    const short* __restrict__ gHin, const short* __restrict__ Sds,
    const short* __restrict__ Ra, const short* __restrict__ Rb,
    const bf* __restrict__ dsz, const short* __restrict__ Rc,
    bf* __restrict__ gHout)
{
    __shared__ short st[64*HID];
    int lane = threadIdx.x & 63, w = threadIdx.x >> 6;
    int m0 = blockIdx.x*64 + w*16;
    int ar = lane & 15, kg = lane >> 4;
    bf8v as_[4], ad_[4];
#pragma unroll
    for (int s=0;s<4;s++)
        as_[s] = *(const bf8v*)&Gs[(size_t)(m0+ar)*HID + s*32 + kg*8];
    if (Sds){
#pragma unroll
        for (int s=0;s<4;s++){
            bf8v g = *(const bf8v*)&gHin[(size_t)(m0+ar)*HID + s*32 + kg*8];
            bf8v sd = *(const bf8v*)&Sds[(size_t)(m0+ar)*HID + s*32 + kg*8];
            bf8v r;
#pragma unroll
            for (int i=0;i<8;i++) r[i] = f2s(s2f(g[i])*s2f(sd[i]));
            ad_[s] = r;
        }
    } else {
#pragma unroll
        for (int s=0;s<4;s++)
            ad_[s] = *(const bf8v*)&Gd[(size_t)(m0+ar)*HID + s*32 + kg*8];
    }
    f4v acc[8];
#pragma unroll
    for (int nt=0;nt<8;nt++){
        acc[nt] = (f4v){0.f,0.f,0.f,0.f};
        const short* bpa = Ra + (nt*16+ar)*HID + kg*8;
        const short* bpb = Rb + (nt*16+ar)*HID + kg*8;
#pragma unroll
        for (int s=0;s<4;s++){
            bf8v ba = *(const bf8v*)(bpa + s*32);
            bf8v bb = *(const bf8v*)(bpb + s*32);
            acc[nt] = __builtin_amdgcn_mfma_f32_16x16x32_bf16(as_[s], ba, acc[nt], 0,0,0);
            acc[nt] = __builtin_amdgcn_mfma_f32_16x16x32_bf16(ad_[s], bb, acc[nt], 0,0,0);
        }
    }
#pragma unroll
    for (int nt=0;nt<8;nt++){
        int j = nt*16 + ar;
#pragma unroll
        for (int r=0;r<4;r++){
            int m = m0 + kg*4 + r;
            float t = acc[nt][r] * b2f(dsz[(size_t)m*HID + j]);
            st[(w*16 + kg*4 + r)*HID + j] = f2s(t);
        }
    }
    __syncthreads();
    bf8v af[4];
#pragma unroll
    for (int s=0;s<4;s++) af[s] = *(const bf8v*)&st[(w*16+ar)*HID + s*32 + kg*8];
    f4v a2[8];
#pragma unroll
    for (int nt=0;nt<8;nt++){
        a2[nt] = (f4v){0.f,0.f,0.f,0.f};
        const short* bp = Rc + (nt*16+ar)*HID + kg*8;
#pragma unroll
        for (int s=0;s<4;s++){
            bf8v bc = *(const bf8v*)(bp + s*32);
            a2[nt] = __builtin_amdgcn_mfma_f32_16x16x32_bf16(af[s], bc, a2[nt], 0,0,0);
        }
    }
#pragma unroll
    for (int nt=0;nt<8;nt++){
        int j = nt*16 + ar;
#pragma unroll
        for (int r=0;r<4;r++){
            gHout[(size_t)(m0 + kg*4 + r)*HID + j] = f2b(a2[nt][r]);
        }
    }
}

// l3 dst pass, scalar-uniform metadata
__global__ __launch_bounds__(128) void k_l3_dst(
    const int* __restrict__ csr, const int* __restrict__ rptr, const int* __restrict__ cnt,
    const float* __restrict__ dgnn, const bf* __restrict__ u, const bf* __restrict__ v,
    const float* __restrict__ A3, const float* __restrict__ B3,
    const float* __restrict__ C3, const float* __restrict__ D3,
    bf* __restrict__ ds3, bf* __restrict__ Gd, float* __restrict__ x3)
{
    __shared__ float rr[2];
    int dst = blockIdx.x, k = threadIdx.x;
    int n = cnt[dst], r0 = rptr[dst];
    float wd = A3[256*HID+k], ck = C3[k];
    float base = b2f(v[dst*HID+k]) + B3[k];
    float hsum = 0.f, dssum = 0.f;
    const short* us = (const short*)u;
    short* dso = (short*)ds3;
#pragma unroll 2
    for (int j=0;j<n;j++){
        int e = csr[r0+j];
        float a = s2f(us[(size_t)(e>>4)*HID + k]) + base + dgnn[e]*wd;
        float sg = sigf(a);
        hsum += a*sg;
        float dv = sg*(1.f + a*(1.f - sg));
        dssum += dv;
        dso[(size_t)e*HID + k] = f2s(dv);
    }
    Gd[dst*HID+k] = f2b(ck*dssum);
    float pv = waveRed(ck*hsum);
    if ((k&63)==0) rr[k>>6] = pv;
    __syncthreads();
    if (k==0) x3[dst] = rr[0] + rr[1] + (float)n*D3[0];
}

// l3 src pass: LDS-staged contiguous ds3 slab -> Gs3 + gdg (=)
__global__ __launch_bounds__(128) void k_l3_src(
    const bf* __restrict__ ds3,
    const float* __restrict__ A3, const float* __restrict__ C3,
    bf* __restrict__ Gs, float* __restrict__ gdg)
{
    __shared__ short sds[2048];
    __shared__ float sQ[16][130];
    int s = blockIdx.x, k = threadIdx.x;
    const bf8v* slab = (const bf8v*)((const short*)ds3 + (size_t)s*2048);
    ((bf8v*)sds)[k]     = slab[k];
    ((bf8v*)sds)[128+k] = slab[128+k];
    __syncthreads();
    float wd = A3[256*HID+k], ck = C3[k];
    float cw = ck*wd;
    float gs = 0.f;
#pragma unroll
    for (int t=0;t<16;t++){
        float dv = s2f(sds[t*128+k]);
        gs += dv;
        sQ[t][k] = dv*cw;
    }
    Gs[s*HID+k] = f2b(ck*gs);
    __syncthreads();
    int t = k >> 3, r = k & 7;
    float pg = 0.f;
#pragma unroll
    for (int i=0;i<16;i++) pg += sQ[t][i + 16*r];
    pg += __shfl_xor(pg,1); pg += __shfl_xor(pg,2); pg += __shfl_xor(pg,4);
    if (r==0) gdg[s*16+t] = pg;
}

// layer-2 bwd src-only
__global__ __launch_bounds__(128) void k_bwd_src(
    const int* __restrict__ gei, const bf* __restrict__ ds2,
    const float* __restrict__ wdp, const bf* __restrict__ gH,
    bf* __restrict__ Gs, float* __restrict__ gdg)
{
    __shared__ short sds[2048];
    __shared__ short sgh[2048];
    __shared__ float sQ[16][130];
    int s = blockIdx.x, k = threadIdx.x;
    const bf8v* slab = (const bf8v*)((const short*)ds2 + (size_t)s*2048);
    ((bf8v*)sds)[k]     = slab[k];
    ((bf8v*)sds)[128+k] = slab[128+k];
    {
        int t = k >> 3, q = k & 7;
        int dst = gei[EGNN + s*16 + t];
        const bf8v* gr = (const bf8v*)((const short*)gH + (size_t)dst*HID);
        ((bf8v*)sgh)[t*16 + q*2]     = gr[q*2];
        ((bf8v*)sgh)[t*16 + q*2 + 1] = gr[q*2+1];
    }
    __syncthreads();
    float wd = wdp[k];
    float gs = 0.f;
#pragma unroll
    for (int t=0;t<16;t++){
        float ga = s2f(sgh[t*128+k]) * s2f(sds[t*128+k]);
        gs += ga;
        sQ[t][k] = ga*wd;
    }
    Gs[s*HID+k] = f2b(gs);
    __syncthreads();
    int t = k >> 3, r = k & 7;
    float pg = 0.f;
#pragma unroll
    for (int i=0;i<16;i++) pg += sQ[t][i + 16*r];
    pg += __shfl_xor(pg,1); pg += __shfl_xor(pg,2); pg += __shfl_xor(pg,4);
    if (r==0) gdg[s*16+t] += pg;
}

// layer-1 bwd
__global__ __launch_bounds__(128) void k_bwd1_src(
    const int* __restrict__ gei, const bf* __restrict__ ds1,
    const float* __restrict__ wdp, const bf* __restrict__ gH,
    float* __restrict__ gdg)
{
    __shared__ short sds[2048];
    __shared__ short sgh[2048];
    __shared__ float sQ[16][130];
    int s = blockIdx.x, k = threadIdx.x;
    const bf8v* slab = (const bf8v*)((const short*)ds1 + (size_t)s*2048);
    ((bf8v*)sds)[k]     = slab[k];
    ((bf8v*)sds)[128+k] = slab[128+k];
    {
        int t = k >> 3, q = k & 7;
        int dst = gei[EGNN + s*16 + t];
        const bf8v* gr = (const bf8v*)((const short*)gH + (size_t)dst*HID);
        ((bf8v*)sgh)[t*16 + q*2]     = gr[q*2];
        ((bf8v*)sgh)[t*16 + q*2 + 1] = gr[q*2+1];
    }
    __syncthreads();
    float wd = wdp[k];
#pragma unroll
    for (int t=0;t<16;t++){
        float ga = s2f(sgh[t*128+k]) * s2f(sds[t*128+k]);
        sQ[t][k] = ga*wd;
    }
    __syncthreads();
    int t = k >> 3, r = k & 7;
    float pg = 0.f;
#pragma unroll
    for (int i=0;i<16;i++) pg += sQ[t][i + 16*r];
    pg += __shfl_xor(pg,1); pg += __shfl_xor(pg,2); pg += __shfl_xor(pg,4);
    if (r==0) gdg[s*16+t] += pg;
}

__global__ __launch_bounds__(256) void k_force_atom(
    const float* __restrict__ pos, const int* __restrict__ gei,
    const int* __restrict__ csr, const int* __restrict__ rptr, const int* __restrict__ cnt,
    const float* __restrict__ dgnn, const float* __restrict__ gdg,
    float* __restrict__ grad)
{
    int T = blockIdx.x*256 + threadIdx.x;
    int i = T >> 3, p = T & 7;
    float px = pos[3*i+0], py = pos[3*i+1], pz = pos[3*i+2];
    float ax=0.f, ay=0.f, az=0.f;
    for (int j=p;j<16;j+=8){
        int e = i*16 + j;
        int o = gei[EGNN+e];
        float c = gdg[e]/dgnn[e];
        ax += c*(px - pos[3*o+0]);
        ay += c*(py - pos[3*o+1]);
        az += c*(pz - pos[3*o+2]);
    }
    int n = cnt[i], r0 = rptr[i];
    for (int j=p;j<n;j+=8){
        int e = csr[r0+j];
        int o = e >> 4;
        float c = gdg[e]/dgnn[e];
        ax += c*(px - pos[3*o+0]);
        ay += c*(py - pos[3*o+1]);
        az += c*(pz - pos[3*o+2]);
    }
    ax += __shfl_xor(ax,1); ax += __shfl_xor(ax,2); ax += __shfl_xor(ax,4);
    ay += __shfl_xor(ay,1); ay += __shfl_xor(ay,2); ay += __shfl_xor(ay,4);
    az += __shfl_xor(az,1); az += __shfl_xor(az,2); az += __shfl_xor(az,4);
    if (p==0){
        grad[3*i+0] += ax;
        grad[3*i+1] += ay;
        grad[3*i+2] += az;
    }
}

__global__ __launch_bounds__(256) void k_final(
    const float* __restrict__ egb, const float* __restrict__ x3,
    const float* __restrict__ grad, float* __restrict__ out)
{
    __shared__ float red[4];
    int m = blockIdx.x, tid = threadIdx.x;
    int i = m*ATOMSM + tid;
    float en = egb[i] + x3[i];
    float v = waveRed(en);
    int wave = tid>>6, lane = tid&63;
    if (lane==0) red[wave] = v;
    __syncthreads();
    if (tid==0) out[m] = red[0]+red[1]+red[2]+red[3];
    float* f = out + MOLS;
    f[3*i+0] = -grad[3*i+0];
    f[3*i+1] = -grad[3*i+1];
    f[3*i+2] = -grad[3*i+2];
}

extern "C" void kernel_launch(void* const* d_in, const int* in_sizes, int n_in,
                              void* d_out, int out_size, void* d_ws, size_t ws_size,
                              hipStream_t stream)
{
    const float* pos  = (const float*)d_in[0];
    const float* feat = (const float*)d_in[1];
    const int* ei  = (const int*)d_in[3];
    const int* gei = (const int*)d_in[4];
    const float* A1f = (const float*)d_in[5];  const float* B1f = (const float*)d_in[6];
    const float* C1f = (const float*)d_in[7];  const float* D1f = (const float*)d_in[8];
    const float* A2f = (const float*)d_in[9];  const float* B2f = (const float*)d_in[10];
    const float* C2f = (const float*)d_in[11]; const float* D2f = (const float*)d_in[12];
    const float* A3f = (const float*)d_in[13]; const float* B3f = (const float*)d_in[14];
    const float* C3f = (const float*)d_in[15]; const float* D3f = (const float*)d_in[16];

    float* w = (float*)d_ws;
    size_t off = 0;
    auto nxt = [&](size_t n)->float*{ float* p = w + off; off += (n + 255) & ~(size_t)255; return p; };
    float* Isum = nxt(NATOMS); float* Bv = nxt(NATOMS); float* cB = nxt(NATOMS);
    float* gB = nxt(NATOMS); float* egb = nxt(NATOMS); float* x3 = nxt(NATOMS);
    int*   cnt  = (int*)nxt(NATOMS);
    int*   rptr = (int*)nxt(NATOMS);
    int*   curs = (int*)nxt(NATOMS);
    int*   csr  = (int*)nxt(EGNN);
    float* dgnn = nxt(EGNN); float* gdgnn = nxt(EGNN); float* gdgb = nxt(EGB);
    float* grad = nxt(3*NATOMS);
    bf* dsz1 = (bf*)nxt(NH/2); bf* dsz2 = (bf*)nxt(NH/2);
    bf* Hs1 = (bf*)nxt(NH/2); bf* Hs2 = (bf*)nxt(NH/2);
    bf* Gs3 = (bf*)nxt(NH/2); bf* Gd3 = (bf*)nxt(NH/2);
    bf* Sds2 = (bf*)nxt(NH/2);
    bf* u1 = (bf*)nxt(NH/2); bf* v1 = (bf*)nxt(NH/2);
    bf* u2 = (bf*)nxt(NH/2); bf* v2 = (bf*)nxt(NH/2);
    bf* v3 = (bf*)nxt(NH/2);
    short* C1t  = (short*)nxt(8192); short* C2t  = (short*)nxt(8192);
    short* A2at = (short*)nxt(8192); short* A2bt = (short*)nxt(8192);
    short* A3at = (short*)nxt(8192); short* A3bt = (short*)nxt(8192);
    short* rA2a = (short*)nxt(8192); short* rA2b = (short*)nxt(8192);
    short* rA3a = (short*)nxt(8192); short* rA3b = (short*)nxt(8192);
    short* rC1  = (short*)nxt(8192); short* rC2  = (short*)nxt(8192);
    bf* ds1 = (bf*)nxt((size_t)EGNN*HID/2);
    bf* ds2 = (bf*)nxt((size_t)EGNN*HID/2);
    bf* ds3 = (bf*)nxt((size_t)EGNN*HID/2);
    // aliases:
    bf* u3  = Hs1;      // Hs1 dead after node_fwd #1
    bf* gH2 = Hs2;      // Hs2 dead after node_fwd #2
    bf* Gs2 = Gs3;      // dead after gx_node_bwd(3->2)
    bf* gH1 = u3;       // u3 dead after l3_dst

    hipMemsetAsync(Isum, 0, NATOMS*sizeof(float), stream);
    hipMemsetAsync(cnt,  0, NATOMS*sizeof(int), stream);
    hipMemsetAsync(grad, 0, 3*NATOMS*sizeof(float), stream);

    k_wprep<<<64,256,0,stream>>>(A2f, C1f, A3f, C2f,
        C1t, C2t, A2at, A2bt, A3at, A3bt, rA2a, rA2b, rA3a, rA3b, rC1, rC2);

    // GB chain (LDS molecule-tile gathers; gbD fused into gbE)
    k_gbA<<<512,256,0,stream>>>(pos, feat, ei, Isum);
    k_gbB<<<NATOMS/256,256,0,stream>>>(feat, Isum, Bv, cB, gB, egb);
    k_gbC<<<512,256,0,stream>>>(pos, feat, ei, Bv, egb, gdgb, gB);
    k_gbE<<<512,256,0,stream>>>(pos, feat, ei, cB, gB, gdgb, grad);

    // dist + CSR build
    k_dist<<<EGNN/256,256,0,stream>>>(pos, gei, dgnn, cnt);
    k_scan<<<MOLS,256,0,stream>>>(cnt, rptr, curs);
    k_fill<<<EGNN/256,256,0,stream>>>(gei, curs, csr);

    // forward
    k_uv1<<<NH/256,256,0,stream>>>(feat, A1f, u1, v1);
    k_edge_fwd_dst<<<NATOMS,128,0,stream>>>(csr, rptr, cnt, dgnn, u1, v1,
                                            A1f+4*HID, B1f, Hs1, ds1, Sds2 /*scratch*/);
    k_node_fwd_uv_mfma<<<NATOMS/64,256,0,stream>>>((const short*)Hs1, cnt, C1t, D1f,
                                                   A2at, A2bt, dsz1, u2, v2);
    k_edge_fwd_dst<<<NATOMS,128,0,stream>>>(csr, rptr, cnt, dgnn, u2, v2,
                                            A2f+256*HID, B2f, Hs2, ds2, Sds2);
    k_node_fwd_uv_mfma<<<NATOMS/64,256,0,stream>>>((const short*)Hs2, cnt, C2t, D2f,
                                                   A3at, A3bt, dsz2, u3, v3);

    // layer-3
    k_l3_dst<<<NATOMS,128,0,stream>>>(csr, rptr, cnt, dgnn, u3, v3,
                                      A3f, B3f, C3f, D3f, ds3, Gd3, x3);
    k_l3_src<<<NATOMS,128,0,stream>>>(ds3, A3f, C3f, Gs3, gdgnn);

    // backward chain
    k_gx_node_bwd_mfma<<<NATOMS/64,256,0,stream>>>((const short*)Gs3, (const short*)Gd3,
        (const short*)nullptr, (const short*)nullptr, rA3a, rA3b, dsz2, rC2, gH2);
    k_bwd_src<<<NATOMS,128,0,stream>>>(gei, ds2, A2f+256*HID, gH2, Gs2, gdgnn);
    k_gx_node_bwd_mfma<<<NATOMS/64,256,0,stream>>>((const short*)Gs2, (const short*)nullptr,
        (const short*)gH2, (const short*)Sds2, rA2a, rA2b, dsz1, rC1, gH1);
    k_bwd1_src<<<NATOMS,128,0,stream>>>(gei, ds1, A1f+4*HID, gH1, gdgnn);
    k_force_atom<<<NATOMS*8/256,256,0,stream>>>(pos, gei, csr, rptr, cnt, dgnn, gdgnn, grad);

    k_final<<<MOLS,256,0,stream>>>(egb, x3, grad, (float*)d_out);
}

// Round 13
// 381.414 us; speedup vs baseline: 1.1421x; 1.0281x over previous
//
#include <hip/hip_runtime.h>
#include <hip/hip_bf16.h>

#define NATOMS 16384
#define MOLS   64
#define ATOMSM 256
#define EGB    524288
#define EGNN   262144
#define HID    128
#define NH     (NATOMS*HID)

#define OFFSETC 0.009f
#define ALPHAC  1.0f
#define BETAC   0.8f
#define GAMMAC  4.85f
#define PREFC   (-138.935456f*(1.0f-1.0f/78.5f))

typedef __hip_bfloat16 bf;
typedef __attribute__((ext_vector_type(8))) short bf8v;
typedef __attribute__((ext_vector_type(4))) float f4v;

__device__ __forceinline__ float b2f(bf x){ return __bfloat162float(x); }
__device__ __forceinline__ bf f2b(float x){ return __float2bfloat16(x); }
__device__ __forceinline__ short f2s(float x){ bf h = f2b(x); return *(short*)&h; }
__device__ __forceinline__ float s2f(short s){
    unsigned int x = ((unsigned int)(unsigned short)s) << 16;
    return __uint_as_float(x);
}
__device__ __forceinline__ float sigf(float x){ return 1.0f/(1.0f+__expf(-x)); }
__device__ __forceinline__ float waveRed(float v){
    v += __shfl_xor(v,32); v += __shfl_xor(v,16); v += __shfl_xor(v,8);
    v += __shfl_xor(v,4);  v += __shfl_xor(v,2);  v += __shfl_xor(v,1);
    return v;
}

// ============ fused gbA + dist (independent, both follow the memset) ============
__global__ __launch_bounds__(256) void k_gbA_dist(
    const float* __restrict__ pos, const float* __restrict__ feat,
    const int* __restrict__ ei, float* __restrict__ Isum,
    const int* __restrict__ gei, float* __restrict__ dgnn, int* __restrict__ cnt)
{
    int tid = threadIdx.x;
    if (blockIdx.x < 512){
        __shared__ float sPx[256], sPy[256], sPz[256], sRho[256], sSr[256];
        __shared__ float sI[256];
        int mbase = (blockIdx.x >> 3) * 256;
        {
            int i = mbase + tid;
            sPx[tid]=pos[3*i]; sPy[tid]=pos[3*i+1]; sPz[tid]=pos[3*i+2];
            float rad = feat[7*i+1], sc = feat[7*i+2];
            float rho = rad - OFFSETC;
            sRho[tid]=rho; sSr[tid]=sc*rho;
            sI[tid]=0.f;
        }
        __syncthreads();
        int T = blockIdx.x*256 + tid;
        int s = T >> 3, p = T & 7;
        int sl = s & 255;
        int e0 = s*32 + p*4;
        float px = sPx[sl], py = sPy[sl], pz = sPz[sl];
        float sr = sSr[sl];
        const int* dP = ei + EGB;
#pragma unroll
        for (int j=0;j<4;j++){
            int dl = dP[e0+j] & 255;
            float dx = px - sPx[dl];
            float dy = py - sPy[dl];
            float dz = pz - sPz[dl];
            float d  = sqrtf(dx*dx+dy*dy+dz*dz + 1e-12f);
            float rho_i = sRho[dl];
            float U = d + sr;
            if (rho_i < U){
                float L = fmaxf(rho_i, fabsf(d - sr));
                float invU = 1.0f/U, invL = 1.0f/L;
                float I = 0.5f*invL - 0.5f*invU
                        + 0.125f*(d - sr*sr/d)*(invU*invU - invL*invL)
                        + 0.25f*__logf(L*invU)/d;
                atomicAdd(&sI[dl], I);
            }
        }
        __syncthreads();
        atomicAdd(&Isum[mbase + tid], sI[tid]);
    } else {
        int e = (blockIdx.x-512)*256 + tid;
        if (e >= EGNN) return;
        int s = gei[e], dd = gei[EGNN+e];
        float dx = pos[3*s+0] - pos[3*dd+0];
        float dy = pos[3*s+1] - pos[3*dd+1];
        float dz = pos[3*s+2] - pos[3*dd+2];
        dgnn[e] = sqrtf(dx*dx+dy*dy+dz*dz + 1e-12f);
        atomicAdd(&cnt[dd], 1);
    }
}

// ============ fused gbB + scan ============
__global__ __launch_bounds__(256) void k_gbB_scan(
    const float* __restrict__ feat, const float* __restrict__ Isum,
    float* __restrict__ Bv, float* __restrict__ cB, float* __restrict__ gB,
    float* __restrict__ egb,
    const int* __restrict__ cnt, int* __restrict__ rptr, int* __restrict__ cursor)
{
    int t = threadIdx.x;
    if (blockIdx.x < 64){
        int i = blockIdx.x*256 + t;
        float q   = feat[7*i+0];
        float rad = feat[7*i+1];
        float rho = rad - OFFSETC;
        float psi = Isum[i]*rho;
        float u = psi*(ALPHAC + psi*(-BETAC + GAMMAC*psi));
        float tt = tanhf(u);
        float B = 1.0f/(1.0f/rho - tt/rad);
        Bv[i] = B;
        float du = ALPHAC + psi*(-2.0f*BETAC + 3.0f*GAMMAC*psi);
        cB[i] = B*B*((1.0f-tt*tt)/rad)*du*rho;
        float Cs = 0.5f*PREFC*q*q;
        egb[i] = Cs/B;
        gB[i]  = -Cs/(B*B);
    } else {
        __shared__ int sc[256];
        int m = blockIdx.x - 64;
        int c = cnt[m*256+t];
        sc[t] = c; __syncthreads();
        for (int off=1; off<256; off<<=1){
            int x = (t>=off) ? sc[t-off] : 0;
            __syncthreads();
            sc[t] += x;
            __syncthreads();
        }
        int ex = m*4096 + sc[t] - c;
        rptr[m*256+t] = ex;
        cursor[m*256+t] = ex;
    }
}

__global__ __launch_bounds__(256) void k_gbC(
    const float* __restrict__ pos, const float* __restrict__ feat,
    const int* __restrict__ ei, const float* __restrict__ Bv,
    float* __restrict__ egb, float* __restrict__ gdgb, float* __restrict__ gB)
{
    __shared__ float sPx[256], sPy[256], sPz[256], sB[256], sQf[256];
    __shared__ float sE[256], sG[256];
    int tid = threadIdx.x;
    int mbase = (blockIdx.x >> 3) * 256;
    {
        int i = mbase + tid;
        sPx[tid]=pos[3*i]; sPy[tid]=pos[3*i+1]; sPz[tid]=pos[3*i+2];
        sB[tid]=Bv[i]; sQf[tid]=feat[7*i+0];
        sE[tid]=0.f; sG[tid]=0.f;
    }
    __syncthreads();
    int T = blockIdx.x*256 + tid;
    int s = T >> 3, p = T & 7;
    int sl = s & 255;
    int e0 = s*32 + p*4;
    float px = sPx[sl], py = sPy[sl], pz = sPz[sl];
    float qs = sQf[sl];
    float Bs = sB[sl];
    float gsrc = 0.f;
    const int* dP = ei + EGB;
#pragma unroll
    for (int j=0;j<4;j++){
        int dl = dP[e0+j] & 255;
        float dx = px - sPx[dl];
        float dy = py - sPy[dl];
        float dz = pz - sPz[dl];
        float d2 = dx*dx+dy*dy+dz*dz + 1e-12f;
        float d  = sqrtf(d2);
        float Bd = sB[dl];
        float C = 0.5f*PREFC*sQf[dl]*qs;
        float P = Bd*Bs;
        float ex = __expf(-d2/(4.f*P));
        float f2 = d2 + P*ex;
        float f  = sqrtf(f2);
        float f3i = 1.f/(f2*f);
        gdgb[e0+j] = -C*d*(1.f - 0.25f*ex)*f3i;
        float common = -C*ex*(1.f + d2/(4.f*P))*0.5f*f3i;
        atomicAdd(&sE[dl], C/f);
        atomicAdd(&sG[dl], common*Bs);
        gsrc += common*Bd;
    }
    gsrc += __shfl_xor(gsrc,1);
    gsrc += __shfl_xor(gsrc,2);
    gsrc += __shfl_xor(gsrc,4);
    if (p==0) atomicAdd(&sG[sl], gsrc);
    __syncthreads();
    atomicAdd(&egb[mbase + tid], sE[tid]);
    atomicAdd(&gB[mbase + tid],  sG[tid]);
}

__global__ __launch_bounds__(256) void k_gbE(
    const float* __restrict__ pos, const float* __restrict__ feat,
    const int* __restrict__ ei, const float* __restrict__ cB,
    const float* __restrict__ gB,
    const float* __restrict__ gdgb, float* __restrict__ grad)
{
    __shared__ float sPx[256], sPy[256], sPz[256], sRho[256], sSr[256], sCg[256];
    __shared__ float sGx[256], sGy[256], sGz[256];
    int tid = threadIdx.x;
    int mbase = (blockIdx.x >> 3) * 256;
    {
        int i = mbase + tid;
        sPx[tid]=pos[3*i]; sPy[tid]=pos[3*i+1]; sPz[tid]=pos[3*i+2];
        float rad = feat[7*i+1], sc = feat[7*i+2];
        float rho = rad - OFFSETC;
        sRho[tid]=rho; sSr[tid]=sc*rho;
        sCg[tid]=cB[i]*gB[i];
        sGx[tid]=0.f; sGy[tid]=0.f; sGz[tid]=0.f;
    }
    __syncthreads();
    int T = blockIdx.x*256 + tid;
    int s = T >> 3, p = T & 7;
    int sl = s & 255;
    int e0 = s*32 + p*4;
    float px = sPx[sl], py = sPy[sl], pz = sPz[sl];
    float sr = sSr[sl];
    float gx=0.f, gy=0.f, gz=0.f;
    const int* dP = ei + EGB;
#pragma unroll
    for (int j=0;j<4;j++){
        int dl = dP[e0+j] & 255;
        float dx = px - sPx[dl];
        float dy = py - sPy[dl];
        float dz = pz - sPz[dl];
        float d2 = dx*dx+dy*dy+dz*dz + 1e-12f;
        float d  = sqrtf(d2);
        float rho_i = sRho[dl];
        float U = d + sr;
        float gd = gdgb[e0+j];
        if (rho_i < U){
            float aa = fabsf(d - sr);
            float L, Lp;
            if (rho_i >= aa){ L = rho_i; Lp = 0.f; }
            else { L = aa; Lp = (d >= sr) ? 1.f : -1.f; }
            float invU = 1.f/U, invL = 1.f/L;
            float invU2=invU*invU, invL2=invL*invL;
            float dIdd = -0.5f*Lp*invL2 + 0.5f*invU2
                + 0.125f*(1.f + sr*sr/d2)*(invU2 - invL2)
                + 0.125f*(d - sr*sr/d)*(2.f*Lp*invL2*invL - 2.f*invU2*invU)
                + 0.25f*((Lp*invL - invU)/d - __logf(L*invU)/d2);
            gd += sCg[dl]*dIdd;
        }
        float c = gd/d;
        gx += c*dx; gy += c*dy; gz += c*dz;
        atomicAdd(&sGx[dl], -c*dx);
        atomicAdd(&sGy[dl], -c*dy);
        atomicAdd(&sGz[dl], -c*dz);
    }
    gx += __shfl_xor(gx,1); gx += __shfl_xor(gx,2); gx += __shfl_xor(gx,4);
    gy += __shfl_xor(gy,1); gy += __shfl_xor(gy,2); gy += __shfl_xor(gy,4);
    gz += __shfl_xor(gz,1); gz += __shfl_xor(gz,2); gz += __shfl_xor(gz,4);
    if (p==0){
        atomicAdd(&sGx[sl], gx);
        atomicAdd(&sGy[sl], gy);
        atomicAdd(&sGz[sl], gz);
    }
    __syncthreads();
    int i = mbase + tid;
    atomicAdd(&grad[3*i+0], sGx[tid]);
    atomicAdd(&grad[3*i+1], sGy[tid]);
    atomicAdd(&grad[3*i+2], sGz[tid]);
}

__global__ __launch_bounds__(256) void k_fill(
    const int* __restrict__ gei, int* __restrict__ cursor, int* __restrict__ csr)
{
    int e = blockIdx.x*256 + threadIdx.x;
    if (e >= EGNN) return;
    int dst = gei[EGNN+e];
    int pos = atomicAdd(&cursor[dst], 1);
    csr[pos] = e;
}

// ============ fused wprep + uv1 ============
__global__ __launch_bounds__(256) void k_pre(
    const float* __restrict__ A2, const float* __restrict__ C1,
    const float* __restrict__ A3, const float* __restrict__ C2,
    short* __restrict__ C1t, short* __restrict__ C2t,
    short* __restrict__ A2at, short* __restrict__ A2bt,
    short* __restrict__ A3at, short* __restrict__ A3bt,
    short* __restrict__ rA2a, short* __restrict__ rA2b,
    short* __restrict__ rA3a, short* __restrict__ rA3b,
    short* __restrict__ rC1, short* __restrict__ rC2,
    const float* __restrict__ feat, const float* __restrict__ A1,
    bf* __restrict__ u1, bf* __restrict__ v1)
{
    if (blockIdx.x < 64){
        int gid = blockIdx.x*256 + threadIdx.x;
        int j = gid >> 7, k = gid & 127;
        C1t[gid]  = f2s(C1[k*HID+j]);
        C2t[gid]  = f2s(C2[k*HID+j]);
        A2at[gid] = f2s(A2[k*HID+j]);
        A2bt[gid] = f2s(A2[(HID+k)*HID+j]);
        A3at[gid] = f2s(A3[k*HID+j]);
        A3bt[gid] = f2s(A3[(HID+k)*HID+j]);
        rA2a[gid] = f2s(A2[gid]);
        rA2b[gid] = f2s(A2[HID*HID+gid]);
        rA3a[gid] = f2s(A3[gid]);
        rA3b[gid] = f2s(A3[HID*HID+gid]);
        rC1[gid]  = f2s(C1[gid]);
        rC2[gid]  = f2s(C2[gid]);
    } else {
        int gid = (blockIdx.x-64)*256 + threadIdx.x;
        int i = gid >> 7, k = gid & 127;
        float q = feat[7*i+0], r = feat[7*i+1];
        u1[gid] = f2b(q*A1[k]       + r*A1[HID+k]);
        v1[gid] = f2b(q*A1[2*HID+k] + r*A1[3*HID+k]);
    }
}

// dst-centric forward, scalar-uniform metadata
__global__ __launch_bounds__(128) void k_edge_fwd_dst(
    const int* __restrict__ csr, const int* __restrict__ rptr, const int* __restrict__ cnt,
    const float* __restrict__ dgnn, const bf* __restrict__ u, const bf* __restrict__ v,
    const float* __restrict__ wdp, const float* __restrict__ bb,
    bf* __restrict__ Hs, bf* __restrict__ dsO, bf* __restrict__ Sds)
{
    int dst = blockIdx.x, k = threadIdx.x;
    int n = cnt[dst], r0 = rptr[dst];
    float wd = wdp[k];
    float base = b2f(v[dst*HID+k]) + bb[k];
    float hsum = 0.f, dssum = 0.f;
    const short* us = (const short*)u;
    short* dso = (short*)dsO;
#pragma unroll 2
    for (int j=0;j<n;j++){
        int e = csr[r0+j];
        float a = s2f(us[(size_t)(e>>4)*HID + k]) + base + dgnn[e]*wd;
        float sg = sigf(a);
        hsum += a*sg;
        float dv = sg*(1.f + a*(1.f - sg));
        dssum += dv;
        dso[(size_t)e*HID + k] = f2s(dv);
    }
    Hs[dst*HID+k] = f2b(hsum);
    Sds[dst*HID+k] = f2b(dssum);
}

// MFMA node forward
__global__ __launch_bounds__(256) void k_node_fwd_uv_mfma(
    const short* __restrict__ Hs, const int* __restrict__ cnt,
    const short* __restrict__ Ct, const float* __restrict__ D,
    const short* __restrict__ Aat, const short* __restrict__ Abt,
    bf* __restrict__ dsz, bf* __restrict__ u, bf* __restrict__ v)
{
    __shared__ short sx[64*HID];
    int lane = threadIdx.x & 63, w = threadIdx.x >> 6;
    int m0 = blockIdx.x*64 + w*16;
    int ar = lane & 15, kg = lane >> 4;
    bf8v af[4];
#pragma unroll
    for (int s=0;s<4;s++) af[s] = *(const bf8v*)&Hs[(size_t)(m0+ar)*HID + s*32 + kg*8];
    f4v acc[8];
#pragma unroll
    for (int nt=0;nt<8;nt++){
        acc[nt] = (f4v){0.f,0.f,0.f,0.f};
        const short* bp = Ct + (nt*16+ar)*HID + kg*8;
#pragma unroll
        for (int s=0;s<4;s++){
            bf8v bv = *(const bf8v*)(bp + s*32);
            acc[nt] = __builtin_amdgcn_mfma_f32_16x16x32_bf16(af[s], bv, acc[nt], 0,0,0);
        }
    }
    float cn[4];
#pragma unroll
    for (int r=0;r<4;r++) cn[r] = (float)cnt[m0 + kg*4 + r];
#pragma unroll
    for (int nt=0;nt<8;nt++){
        int j = nt*16 + ar;
        float Dj = D[j];
#pragma unroll
        for (int r=0;r<4;r++){
            int m = m0 + kg*4 + r;
            float zv = acc[nt][r] + cn[r]*Dj;
            float sg = sigf(zv);
            dsz[(size_t)m*HID + j] = f2b(sg*(1.f + zv*(1.f - sg)));
            sx[(w*16 + kg*4 + r)*HID + j] = f2s(zv*sg);
        }
    }
    __syncthreads();
#pragma unroll
    for (int s=0;s<4;s++) af[s] = *(const bf8v*)&sx[(w*16+ar)*HID + s*32 + kg*8];
    f4v au[8], av[8];
#pragma unroll
    for (int nt=0;nt<8;nt++){
        au[nt] = (f4v){0.f,0.f,0.f,0.f};
        av[nt] = (f4v){0.f,0.f,0.f,0.f};
        const short* bpa = Aat + (nt*16+ar)*HID + kg*8;
        const short* bpb = Abt + (nt*16+ar)*HID + kg*8;
#pragma unroll
        for (int s=0;s<4;s++){
            bf8v ba = *(const bf8v*)(bpa + s*32);
            bf8v bb = *(const bf8v*)(bpb + s*32);
            au[nt] = __builtin_amdgcn_mfma_f32_16x16x32_bf16(af[s], ba, au[nt], 0,0,0);
            av[nt] = __builtin_amdgcn_mfma_f32_16x16x32_bf16(af[s], bb, av[nt], 0,0,0);
        }
    }
#pragma unroll
    for (int nt=0;nt<8;nt++){
        int j = nt*16 + ar;
#pragma unroll
        for (int r=0;r<4;r++){
            int m = m0 + kg*4 + r;
            u[(size_t)m*HID + j] = f2b(au[nt][r]);
            v[(size_t)m*HID + j] = f2b(av[nt][r]);
        }
    }
}

// MFMA node backward. If Sds != nullptr: Gd frag = gHin ⊙ Sds.
__global__ __launch_bounds__(256) void k_gx_node_bwd_mfma(
    const short* __restrict__ Gs, const short* __restrict__ Gd,
    const short* __restrict__ gHin, const short* __restrict__ Sds,
    const short* __restrict__ Ra, const short* __restrict__ Rb,
    const bf* __restrict__ dsz, const short* __restrict__ Rc,
    bf* __restrict__ gHout)
{
    __shared__ short st[64*HID];
    int lane = threadIdx.x & 63, w = threadIdx.x >> 6;
    int m0 = blockIdx.x*64 + w*16;
    int ar = lane & 15, kg = lane >> 4;
    bf8v as_[4], ad_[4];
#pragma unroll
    for (int s=0;s<4;s++)
        as_[s] = *(const bf8v*)&Gs[(size_t)(m0+ar)*HID + s*32 + kg*8];
    if (Sds){
#pragma unroll
        for (int s=0;s<4;s++){
            bf8v g = *(const bf8v*)&gHin[(size_t)(m0+ar)*HID + s*32 + kg*8];
            bf8v sd = *(const bf8v*)&Sds[(size_t)(m0+ar)*HID + s*32 + kg*8];
            bf8v r;
#pragma unroll
            for (int i=0;i<8;i++) r[i] = f2s(s2f(g[i])*s2f(sd[i]));
            ad_[s] = r;
        }
    } else {
#pragma unroll
        for (int s=0;s<4;s++)
            ad_[s] = *(const bf8v*)&Gd[(size_t)(m0+ar)*HID + s*32 + kg*8];
    }
    f4v acc[8];
#pragma unroll
    for (int nt=0;nt<8;nt++){
        acc[nt] = (f4v){0.f,0.f,0.f,0.f};
        const short* bpa = Ra + (nt*16+ar)*HID + kg*8;
        const short* bpb = Rb + (nt*16+ar)*HID + kg*8;
#pragma unroll
        for (int s=0;s<4;s++){
            bf8v ba = *(const bf8v*)(bpa + s*32);
            bf8v bb = *(const bf8v*)(bpb + s*32);
            acc[nt] = __builtin_amdgcn_mfma_f32_16x16x32_bf16(as_[s], ba, acc[nt], 0,0,0);
            acc[nt] = __builtin_amdgcn_mfma_f32_16x16x32_bf16(ad_[s], bb, acc[nt], 0,0,0);
        }
    }
#pragma unroll
    for (int nt=0;nt<8;nt++){
        int j = nt*16 + ar;
#pragma unroll
        for (int r=0;r<4;r++){
            int m = m0 + kg*4 + r;
            float t = acc[nt][r] * b2f(dsz[(size_t)m*HID + j]);
            st[(w*16 + kg*4 + r)*HID + j] = f2s(t);
        }
    }
    __syncthreads();
    bf8v af[4];
#pragma unroll
    for (int s=0;s<4;s++) af[s] = *(const bf8v*)&st[(w*16+ar)*HID + s*32 + kg*8];
    f4v a2[8];
#pragma unroll
    for (int nt=0;nt<8;nt++){
        a2[nt] = (f4v){0.f,0.f,0.f,0.f};
        const short* bp = Rc + (nt*16+ar)*HID + kg*8;
#pragma unroll
        for (int s=0;s<4;s++){
            bf8v bc = *(const bf8v*)(bp + s*32);
            a2[nt] = __builtin_amdgcn_mfma_f32_16x16x32_bf16(af[s], bc, a2[nt], 0,0,0);
        }
    }
#pragma unroll
    for (int nt=0;nt<8;nt++){
        int j = nt*16 + ar;
#pragma unroll
        for (int r=0;r<4;r++){
            gHout[(size_t)(m0 + kg*4 + r)*HID + j] = f2b(a2[nt][r]);
        }
    }
}

// l3 dst pass
__global__ __launch_bounds__(128) void k_l3_dst(
    const int* __restrict__ csr, const int* __restrict__ rptr, const int* __restrict__ cnt,
    const float* __restrict__ dgnn, const bf* __restrict__ u, const bf* __restrict__ v,
    const float* __restrict__ A3, const float* __restrict__ B3,
    const float* __restrict__ C3, const float* __restrict__ D3,
    bf* __restrict__ ds3, bf* __restrict__ Gd, float* __restrict__ x3)
{
    __shared__ float rr[2];
    int dst = blockIdx.x, k = threadIdx.x;
    int n = cnt[dst], r0 = rptr[dst];
    float wd = A3[256*HID+k], ck = C3[k];
    float base = b2f(v[dst*HID+k]) + B3[k];
    float hsum = 0.f, dssum = 0.f;
    const short* us = (const short*)u;
    short* dso = (short*)ds3;
#pragma unroll 2
    for (int j=0;j<n;j++){
        int e = csr[r0+j];
        float a = s2f(us[(size_t)(e>>4)*HID + k]) + base + dgnn[e]*wd;
        float sg = sigf(a);
        hsum += a*sg;
        float dv = sg*(1.f + a*(1.f - sg));
        dssum += dv;
        dso[(size_t)e*HID + k] = f2s(dv);
    }
    Gd[dst*HID+k] = f2b(ck*dssum);
    float pv = waveRed(ck*hsum);
    if ((k&63)==0) rr[k>>6] = pv;
    __syncthreads();
    if (k==0) x3[dst] = rr[0] + rr[1] + (float)n*D3[0];
}

// l3 src pass
__global__ __launch_bounds__(128) void k_l3_src(
    const bf* __restrict__ ds3,
    const float* __restrict__ A3, const float* __restrict__ C3,
    bf* __restrict__ Gs, float* __restrict__ gdg)
{
    __shared__ short sds[2048];
    __shared__ float sQ[16][130];
    int s = blockIdx.x, k = threadIdx.x;
    const bf8v* slab = (const bf8v*)((const short*)ds3 + (size_t)s*2048);
    ((bf8v*)sds)[k]     = slab[k];
    ((bf8v*)sds)[128+k] = slab[128+k];
    __syncthreads();
    float wd = A3[256*HID+k], ck = C3[k];
    float cw = ck*wd;
    float gs = 0.f;
#pragma unroll
    for (int t=0;t<16;t++){
        float dv = s2f(sds[t*128+k]);
        gs += dv;
        sQ[t][k] = dv*cw;
    }
    Gs[s*HID+k] = f2b(ck*gs);
    __syncthreads();
    int t = k >> 3, r = k & 7;
    float pg = 0.f;
#pragma unroll
    for (int i=0;i<16;i++) pg += sQ[t][i + 16*r];
    pg += __shfl_xor(pg,1); pg += __shfl_xor(pg,2); pg += __shfl_xor(pg,4);
    if (r==0) gdg[s*16+t] = pg;
}

// layer-2 bwd src-only
__global__ __launch_bounds__(128) void k_bwd_src(
    const int* __restrict__ gei, const bf* __restrict__ ds2,
    const float* __restrict__ wdp, const bf* __restrict__ gH,
    bf* __restrict__ Gs, float* __restrict__ gdg)
{
    __shared__ short sds[2048];
    __shared__ short sgh[2048];
    __shared__ float sQ[16][130];
    int s = blockIdx.x, k = threadIdx.x;
    const bf8v* slab = (const bf8v*)((const short*)ds2 + (size_t)s*2048);
    ((bf8v*)sds)[k]     = slab[k];
    ((bf8v*)sds)[128+k] = slab[128+k];
    {
        int t = k >> 3, q = k & 7;
        int dst = gei[EGNN + s*16 + t];
        const bf8v* gr = (const bf8v*)((const short*)gH + (size_t)dst*HID);
        ((bf8v*)sgh)[t*16 + q*2]     = gr[q*2];
        ((bf8v*)sgh)[t*16 + q*2 + 1] = gr[q*2+1];
    }
    __syncthreads();
    float wd = wdp[k];
    float gs = 0.f;
#pragma unroll
    for (int t=0;t<16;t++){
        float ga = s2f(sgh[t*128+k]) * s2f(sds[t*128+k]);
        gs += ga;
        sQ[t][k] = ga*wd;
    }
    Gs[s*HID+k] = f2b(gs);
    __syncthreads();
    int t = k >> 3, r = k & 7;
    float pg = 0.f;
#pragma unroll
    for (int i=0;i<16;i++) pg += sQ[t][i + 16*r];
    pg += __shfl_xor(pg,1); pg += __shfl_xor(pg,2); pg += __shfl_xor(pg,4);
    if (r==0) gdg[s*16+t] += pg;
}

// layer-1 bwd
__global__ __launch_bounds__(128) void k_bwd1_src(
    const int* __restrict__ gei, const bf* __restrict__ ds1,
    const float* __restrict__ wdp, const bf* __restrict__ gH,
    float* __restrict__ gdg)
{
    __shared__ short sds[2048];
    __shared__ short sgh[2048];
    __shared__ float sQ[16][130];
    int s = blockIdx.x, k = threadIdx.x;
    const bf8v* slab = (const bf8v*)((const short*)ds1 + (size_t)s*2048);
    ((bf8v*)sds)[k]     = slab[k];
    ((bf8v*)sds)[128+k] = slab[128+k];
    {
        int t = k >> 3, q = k & 7;
        int dst = gei[EGNN + s*16 + t];
        const bf8v* gr = (const bf8v*)((const short*)gH + (size_t)dst*HID);
        ((bf8v*)sgh)[t*16 + q*2]     = gr[q*2];
        ((bf8v*)sgh)[t*16 + q*2 + 1] = gr[q*2+1];
    }
    __syncthreads();
    float wd = wdp[k];
#pragma unroll
    for (int t=0;t<16;t++){
        float ga = s2f(sgh[t*128+k]) * s2f(sds[t*128+k]);
        sQ[t][k] = ga*wd;
    }
    __syncthreads();
    int t = k >> 3, r = k & 7;
    float pg = 0.f;
#pragma unroll
    for (int i=0;i<16;i++) pg += sQ[t][i + 16*r];
    pg += __shfl_xor(pg,1); pg += __shfl_xor(pg,2); pg += __shfl_xor(pg,4);
    if (r==0) gdg[s*16+t] += pg;
}

// forces: writes output directly, f = -(grad_gb + gnn)
__global__ __launch_bounds__(256) void k_force_atom(
    const float* __restrict__ pos, const int* __restrict__ gei,
    const int* __restrict__ csr, const int* __restrict__ rptr, const int* __restrict__ cnt,
    const float* __restrict__ dgnn, const float* __restrict__ gdg,
    const float* __restrict__ grad, float* __restrict__ fout)
{
    int T = blockIdx.x*256 + threadIdx.x;
    int i = T >> 3, p = T & 7;
    float px = pos[3*i+0], py = pos[3*i+1], pz = pos[3*i+2];
    float ax=0.f, ay=0.f, az=0.f;
    for (int j=p;j<16;j+=8){
        int e = i*16 + j;
        int o = gei[EGNN+e];
        float c = gdg[e]/dgnn[e];
        ax += c*(px - pos[3*o+0]);
        ay += c*(py - pos[3*o+1]);
        az += c*(pz - pos[3*o+2]);
    }
    int n = cnt[i], r0 = rptr[i];
    for (int j=p;j<n;j+=8){
        int e = csr[r0+j];
        int o = e >> 4;
        float c = gdg[e]/dgnn[e];
        ax += c*(px - pos[3*o+0]);
        ay += c*(py - pos[3*o+1]);
        az += c*(pz - pos[3*o+2]);
    }
    ax += __shfl_xor(ax,1); ax += __shfl_xor(ax,2); ax += __shfl_xor(ax,4);
    ay += __shfl_xor(ay,1); ay += __shfl_xor(ay,2); ay += __shfl_xor(ay,4);
    az += __shfl_xor(az,1); az += __shfl_xor(az,2); az += __shfl_xor(az,4);
    if (p==0){
        fout[3*i+0] = -(grad[3*i+0] + ax);
        fout[3*i+1] = -(grad[3*i+1] + ay);
        fout[3*i+2] = -(grad[3*i+2] + az);
    }
}

// energies only
__global__ __launch_bounds__(256) void k_final(
    const float* __restrict__ egb, const float* __restrict__ x3,
    float* __restrict__ out)
{
    __shared__ float red[4];
    int m = blockIdx.x, tid = threadIdx.x;
    int i = m*ATOMSM + tid;
    float en = egb[i] + x3[i];
    float v = waveRed(en);
    int wave = tid>>6, lane = tid&63;
    if (lane==0) red[wave] = v;
    __syncthreads();
    if (tid==0) out[m] = red[0]+red[1]+red[2]+red[3];
}

extern "C" void kernel_launch(void* const* d_in, const int* in_sizes, int n_in,
                              void* d_out, int out_size, void* d_ws, size_t ws_size,
                              hipStream_t stream)
{
    const float* pos  = (const float*)d_in[0];
    const float* feat = (const float*)d_in[1];
    const int* ei  = (const int*)d_in[3];
    const int* gei = (const int*)d_in[4];
    const float* A1f = (const float*)d_in[5];  const float* B1f = (const float*)d_in[6];
    const float* C1f = (const float*)d_in[7];  const float* D1f = (const float*)d_in[8];
    const float* A2f = (const float*)d_in[9];  const float* B2f = (const float*)d_in[10];
    const float* C2f = (const float*)d_in[11]; const float* D2f = (const float*)d_in[12];
    const float* A3f = (const float*)d_in[13]; const float* B3f = (const float*)d_in[14];
    const float* C3f = (const float*)d_in[15]; const float* D3f = (const float*)d_in[16];

    float* w = (float*)d_ws;
    size_t off = 0;
    auto nxt = [&](size_t n)->float*{ float* p = w + off; off += (n + 255) & ~(size_t)255; return p; };
    // contiguous zero-init region: Isum | cnt | grad  (5*NATOMS floats)
    float* Isum = nxt(NATOMS);
    int*   cnt  = (int*)nxt(NATOMS);
    float* grad = nxt(3*NATOMS);
    float* Bv = nxt(NATOMS); float* cB = nxt(NATOMS);
    float* gB = nxt(NATOMS); float* egb = nxt(NATOMS); float* x3 = nxt(NATOMS);
    int*   rptr = (int*)nxt(NATOMS);
    int*   curs = (int*)nxt(NATOMS);
    int*   csr  = (int*)nxt(EGNN);
    float* dgnn = nxt(EGNN); float* gdgnn = nxt(EGNN); float* gdgb = nxt(EGB);
    bf* dsz1 = (bf*)nxt(NH/2); bf* dsz2 = (bf*)nxt(NH/2);
    bf* Hs1 = (bf*)nxt(NH/2); bf* Hs2 = (bf*)nxt(NH/2);
    bf* Gs3 = (bf*)nxt(NH/2); bf* Gd3 = (bf*)nxt(NH/2);
    bf* Sds2 = (bf*)nxt(NH/2);
    bf* u1 = (bf*)nxt(NH/2); bf* v1 = (bf*)nxt(NH/2);
    bf* u2 = (bf*)nxt(NH/2); bf* v2 = (bf*)nxt(NH/2);
    bf* v3 = (bf*)nxt(NH/2);
    short* C1t  = (short*)nxt(8192); short* C2t  = (short*)nxt(8192);
    short* A2at = (short*)nxt(8192); short* A2bt = (short*)nxt(8192);
    short* A3at = (short*)nxt(8192); short* A3bt = (short*)nxt(8192);
    short* rA2a = (short*)nxt(8192); short* rA2b = (short*)nxt(8192);
    short* rA3a = (short*)nxt(8192); short* rA3b = (short*)nxt(8192);
    short* rC1  = (short*)nxt(8192); short* rC2  = (short*)nxt(8192);
    bf* ds1 = (bf*)nxt((size_t)EGNN*HID/2);
    bf* ds2 = (bf*)nxt((size_t)EGNN*HID/2);
    bf* ds3 = (bf*)nxt((size_t)EGNN*HID/2);
    // aliases:
    bf* u3  = Hs1;      // Hs1 dead after node_fwd #1
    bf* gH2 = Hs2;      // Hs2 dead after node_fwd #2
    bf* Gs2 = Gs3;      // dead after gx_node_bwd(3->2)
    bf* gH1 = u3;       // u3 dead after l3_dst

    // single combined zero-init (Isum|cnt|grad are contiguous)
    hipMemsetAsync(Isum, 0, (size_t)5*NATOMS*sizeof(float), stream);

    // preprocessing (weights + layer-1 uv)
    k_pre<<<64+NH/256,256,0,stream>>>(A2f, C1f, A3f, C2f,
        C1t, C2t, A2at, A2bt, A3at, A3bt, rA2a, rA2b, rA3a, rA3b, rC1, rC2,
        feat, A1f, u1, v1);

    // GB + dist fused stage
    k_gbA_dist<<<512+EGNN/256,256,0,stream>>>(pos, feat, ei, Isum, gei, dgnn, cnt);
    k_gbB_scan<<<128,256,0,stream>>>(feat, Isum, Bv, cB, gB, egb, cnt, rptr, curs);
    k_fill<<<EGNN/256,256,0,stream>>>(gei, curs, csr);
    k_gbC<<<512,256,0,stream>>>(pos, feat, ei, Bv, egb, gdgb, gB);
    k_gbE<<<512,256,0,stream>>>(pos, feat, ei, cB, gB, gdgb, grad);

    // forward
    k_edge_fwd_dst<<<NATOMS,128,0,stream>>>(csr, rptr, cnt, dgnn, u1, v1,
                                            A1f+4*HID, B1f, Hs1, ds1, Sds2 /*scratch*/);
    k_node_fwd_uv_mfma<<<NATOMS/64,256,0,stream>>>((const short*)Hs1, cnt, C1t, D1f,
                                                   A2at, A2bt, dsz1, u2, v2);
    k_edge_fwd_dst<<<NATOMS,128,0,stream>>>(csr, rptr, cnt, dgnn, u2, v2,
                                            A2f+256*HID, B2f, Hs2, ds2, Sds2);
    k_node_fwd_uv_mfma<<<NATOMS/64,256,0,stream>>>((const short*)Hs2, cnt, C2t, D2f,
                                                   A3at, A3bt, dsz2, u3, v3);

    // layer-3
    k_l3_dst<<<NATOMS,128,0,stream>>>(csr, rptr, cnt, dgnn, u3, v3,
                                      A3f, B3f, C3f, D3f, ds3, Gd3, x3);
    k_l3_src<<<NATOMS,128,0,stream>>>(ds3, A3f, C3f, Gs3, gdgnn);

    // backward chain
    k_gx_node_bwd_mfma<<<NATOMS/64,256,0,stream>>>((const short*)Gs3, (const short*)Gd3,
        (const short*)nullptr, (const short*)nullptr, rA3a, rA3b, dsz2, rC2, gH2);
    k_bwd_src<<<NATOMS,128,0,stream>>>(gei, ds2, A2f+256*HID, gH2, Gs2, gdgnn);
    k_gx_node_bwd_mfma<<<NATOMS/64,256,0,stream>>>((const short*)Gs2, (const short*)nullptr,
        (const short*)gH2, (const short*)Sds2, rA2a, rA2b, dsz1, rC1, gH1);
    k_bwd1_src<<<NATOMS,128,0,stream>>>(gei, ds1, A1f+4*HID, gH1, gdgnn);

    // outputs
    k_force_atom<<<NATOMS*8/256,256,0,stream>>>(pos, gei, csr, rptr, cnt, dgnn, gdgnn,
                                                grad, (float*)d_out + MOLS);
    k_final<<<MOLS,256,0,stream>>>(egb, x3, (float*)d_out);
}